// Round 1
// baseline (1104.694 us; speedup 1.0000x reference)
//
#include <hip/hip_runtime.h>
#include <math.h>

#define N_NODES 50000
#define N_EDGES 800000
#define D_IN 512
#define D_LAT 256
#define D_EMB 64
#define NEG_SLOPE 0.2f

__device__ __forceinline__ float wave_reduce_sum(float v) {
#pragma unroll
  for (int off = 32; off > 0; off >>= 1) v += __shfl_xor(v, off, 64);
  return v;
}

// ---------------------------------------------------------------------------
// Tiled f32 GEMM: C[M,N] = A[M,K] @ (TRANSB ? B[N,K]^T : B[K,N])
// BM=BN=64, BK=16, 256 threads, 4x4 micro-tile. N % 64 == 0, K % 16 == 0
// required (true for all four calls); M guarded.
// ---------------------------------------------------------------------------
template <int TRANSB>
__global__ __launch_bounds__(256) void gemm_f32(const float* __restrict__ A,
                                                const float* __restrict__ B,
                                                float* __restrict__ C, int M,
                                                int N, int K) {
  const int BM = 64, BN = 64, BK = 16;
  __shared__ float As[BK][BM + 1];
  __shared__ float Bs[BK][BN + 1];
  int tid = threadIdx.x;
  int bm = blockIdx.y * BM, bn = blockIdx.x * BN;
  int tm = (tid / 16) * 4, tn = (tid % 16) * 4;
  float acc[4][4] = {};

  int am = tid / 4;         // 0..63 (row within A tile)
  int ak = (tid % 4) * 4;   // 0,4,8,12

  for (int k0 = 0; k0 < K; k0 += BK) {
    // load A tile (64 x 16)
    {
      int gm = bm + am;
      float4 a = make_float4(0.f, 0.f, 0.f, 0.f);
      if (gm < M) a = *(const float4*)(A + (size_t)gm * K + k0 + ak);
      As[ak + 0][am] = a.x;
      As[ak + 1][am] = a.y;
      As[ak + 2][am] = a.z;
      As[ak + 3][am] = a.w;
    }
    if (TRANSB) {
      // B[N,K]: Bs[k][n] = B[bn+n][k0+k]
      int n = tid / 4, kk = (tid % 4) * 4;
      float4 b = *(const float4*)(B + (size_t)(bn + n) * K + k0 + kk);
      Bs[kk + 0][n] = b.x;
      Bs[kk + 1][n] = b.y;
      Bs[kk + 2][n] = b.z;
      Bs[kk + 3][n] = b.w;
    } else {
      // B[K,N]: Bs[k][n] = B[k0+k][bn+n]
      int kk = tid / 16, n4 = (tid % 16) * 4;
      float4 b = *(const float4*)(B + (size_t)(k0 + kk) * N + bn + n4);
      Bs[kk][n4 + 0] = b.x;
      Bs[kk][n4 + 1] = b.y;
      Bs[kk][n4 + 2] = b.z;
      Bs[kk][n4 + 3] = b.w;
    }
    __syncthreads();
#pragma unroll
    for (int k = 0; k < BK; k++) {
      float a0 = As[k][tm + 0], a1 = As[k][tm + 1], a2 = As[k][tm + 2],
            a3 = As[k][tm + 3];
      float b0 = Bs[k][tn + 0], b1 = Bs[k][tn + 1], b2 = Bs[k][tn + 2],
            b3 = Bs[k][tn + 3];
      acc[0][0] += a0 * b0; acc[0][1] += a0 * b1; acc[0][2] += a0 * b2; acc[0][3] += a0 * b3;
      acc[1][0] += a1 * b0; acc[1][1] += a1 * b1; acc[1][2] += a1 * b2; acc[1][3] += a1 * b3;
      acc[2][0] += a2 * b0; acc[2][1] += a2 * b1; acc[2][2] += a2 * b2; acc[2][3] += a2 * b3;
      acc[3][0] += a3 * b0; acc[3][1] += a3 * b1; acc[3][2] += a3 * b2; acc[3][3] += a3 * b3;
    }
    __syncthreads();
  }
#pragma unroll
  for (int i = 0; i < 4; i++) {
    int gm = bm + tm + i;
    if (gm < M) {
#pragma unroll
      for (int j = 0; j < 4; j++) C[(size_t)gm * N + bn + tn + j] = acc[i][j];
    }
  }
}

// ---------------------------------------------------------------------------
// Per-node attention logits: als[i] = h1[i]·a_src, ald[i] = h1[i]·a_dst
// One wave per node (4 waves / 256-thread block).
// ---------------------------------------------------------------------------
__global__ __launch_bounds__(256) void node_logits(
    const float* __restrict__ h1, const float* __restrict__ a_src,
    const float* __restrict__ a_dst, float* __restrict__ als,
    float* __restrict__ ald) {
  int wave = threadIdx.x / 64, lane = threadIdx.x % 64;
  int node = blockIdx.x * 4 + wave;
  if (node >= N_NODES) return;
  float4 h = *(const float4*)(h1 + (size_t)node * D_LAT + lane * 4);
  float4 as4 = *(const float4*)(a_src + lane * 4);
  float4 ad4 = *(const float4*)(a_dst + lane * 4);
  float s = h.x * as4.x + h.y * as4.y + h.z * as4.z + h.w * as4.w;
  float d = h.x * ad4.x + h.y * ad4.y + h.z * ad4.z + h.w * ad4.w;
  s = wave_reduce_sum(s);
  d = wave_reduce_sum(d);
  if (lane == 0) {
    als[node] = s;
    ald[node] = d;
  }
}

__global__ void hist_kernel(const int* __restrict__ dst,
                            int* __restrict__ counts) {
  int e = blockIdx.x * blockDim.x + threadIdx.x;
  if (e < N_EDGES) atomicAdd(&counts[dst[e]], 1);
}

// single-block exclusive scan of counts[N_NODES] -> rowptr[N_NODES+1]
__global__ __launch_bounds__(1024) void scan_kernel(
    const int* __restrict__ counts, int* __restrict__ rowptr) {
  __shared__ int part[1024];
  const int n = N_NODES;
  int tid = threadIdx.x;
  const int per = (n + 1023) / 1024;
  int base = tid * per;
  int sum = 0;
  for (int i = 0; i < per; i++) {
    int idx = base + i;
    if (idx < n) sum += counts[idx];
  }
  part[tid] = sum;
  __syncthreads();
  for (int off = 1; off < 1024; off <<= 1) {
    int v = (tid >= off) ? part[tid - off] : 0;
    __syncthreads();
    part[tid] += v;
    __syncthreads();
  }
  int run = (tid == 0) ? 0 : part[tid - 1];
  for (int i = 0; i < per; i++) {
    int idx = base + i;
    if (idx < n) {
      rowptr[idx] = run;
      run += counts[idx];
    }
  }
  if (tid == 0) rowptr[n] = part[1023];
}

// bucket edges by dst; store src index and leaky-relu logit, CSR order
__global__ void scatter_kernel(const int* __restrict__ src,
                               const int* __restrict__ dst,
                               const float* __restrict__ als,
                               const float* __restrict__ ald,
                               const int* __restrict__ rowptr,
                               int* __restrict__ fill, int* __restrict__ ssrc,
                               float* __restrict__ slogit) {
  int e = blockIdx.x * blockDim.x + threadIdx.x;
  if (e >= N_EDGES) return;
  int s = src[e], d = dst[e];
  int pos = rowptr[d] + atomicAdd(&fill[d], 1);
  float x = als[s] + ald[d];
  slogit[pos] = (x > 0.f) ? x : NEG_SLOPE * x;
  ssrc[pos] = s;
}

// segment softmax + weighted gather + ELU. One wave per node.
__global__ __launch_bounds__(256) void agg_kernel(
    const float* __restrict__ feat, const int* __restrict__ rowptr,
    const int* __restrict__ ssrc, const float* __restrict__ slogit,
    float* __restrict__ out) {
  int wave = threadIdx.x / 64, lane = threadIdx.x % 64;
  int node = blockIdx.x * 4 + wave;
  if (node >= N_NODES) return;
  int beg = rowptr[node], end = rowptr[node + 1];
  float m = -INFINITY;
  for (int e = beg; e < end; e++) m = fmaxf(m, slogit[e]);
  float ssum = 0.f;
  for (int e = beg; e < end; e++) ssum += __expf(slogit[e] - m);
  float inv = (ssum > 0.f) ? 1.f / ssum : 0.f;
  float4 acc = make_float4(0.f, 0.f, 0.f, 0.f);
  for (int e = beg; e < end; e++) {
    float a = __expf(slogit[e] - m) * inv;
    int s = ssrc[e];
    float4 h = *(const float4*)(feat + (size_t)s * D_LAT + lane * 4);
    acc.x += a * h.x;
    acc.y += a * h.y;
    acc.z += a * h.z;
    acc.w += a * h.w;
  }
  float4 r;
  r.x = acc.x > 0.f ? acc.x : (__expf(acc.x) - 1.f);
  r.y = acc.y > 0.f ? acc.y : (__expf(acc.y) - 1.f);
  r.z = acc.z > 0.f ? acc.z : (__expf(acc.z) - 1.f);
  r.w = acc.w > 0.f ? acc.w : (__expf(acc.w) - 1.f);
  *(float4*)(out + (size_t)node * D_LAT + lane * 4) = r;
}

extern "C" void kernel_launch(void* const* d_in, const int* in_sizes, int n_in,
                              void* d_out, int out_size, void* d_ws,
                              size_t ws_size, hipStream_t stream) {
  const float* x = (const float*)d_in[0];
  const float* W1 = (const float*)d_in[1];
  const float* a1s = (const float*)d_in[2];
  const float* a1d = (const float*)d_in[3];
  const float* W2 = (const float*)d_in[4];
  const int* ge = (const int*)d_in[5];
  const int* esrc = ge;
  const int* edst = ge + N_EDGES;

  float* out = (float*)d_out;
  float* emb = out;                             // [N, 64]
  float* recon = out + (size_t)N_NODES * D_EMB; // [N, 512]

  char* w = (char*)d_ws;
  float* h1 = (float*)w;      w += (size_t)N_NODES * D_LAT * 4;  // reused as dec_inter
  float* inter = (float*)w;   w += (size_t)N_NODES * D_LAT * 4;  // reused as h3
  float* als = (float*)w;     w += (size_t)N_NODES * 4;
  float* ald = (float*)w;     w += (size_t)N_NODES * 4;
  int* counts = (int*)w;      w += (size_t)N_NODES * 4;
  int* rowptr = (int*)w;      w += (size_t)(N_NODES + 4) * 4;
  int* fill = (int*)w;        w += (size_t)N_NODES * 4;
  int* ssrc = (int*)w;        w += (size_t)N_EDGES * 4;
  float* slogit = (float*)w;  w += (size_t)N_EDGES * 4;

  hipMemsetAsync(counts, 0, N_NODES * 4, stream);
  hipMemsetAsync(fill, 0, N_NODES * 4, stream);

  dim3 b256(256);
  int mblk = (N_NODES + 63) / 64;

  // 1. h1 = x @ W1        [N,512]@[512,256]
  gemm_f32<0><<<dim3(D_LAT / 64, mblk), b256, 0, stream>>>(x, W1, h1, N_NODES,
                                                           D_LAT, D_IN);
  // 2. per-node logits
  node_logits<<<(N_NODES + 3) / 4, b256, 0, stream>>>(h1, a1s, a1d, als, ald);
  // 3-5. CSR by dst
  hist_kernel<<<(N_EDGES + 255) / 256, b256, 0, stream>>>(edst, counts);
  scan_kernel<<<1, 1024, 0, stream>>>(counts, rowptr);
  scatter_kernel<<<(N_EDGES + 255) / 256, b256, 0, stream>>>(
      esrc, edst, als, ald, rowptr, fill, ssrc, slogit);
  // 6. agg1 + elu -> inter
  agg_kernel<<<(N_NODES + 3) / 4, b256, 0, stream>>>(h1, rowptr, ssrc, slogit,
                                                     inter);
  // 7. emb = inter @ W2   [N,256]@[256,64]
  gemm_f32<0><<<dim3(D_EMB / 64, mblk), b256, 0, stream>>>(inter, W2, emb,
                                                           N_NODES, D_EMB,
                                                           D_LAT);
  // 8. h3 = emb @ W2^T    [N,64]@[64,256]  (overwrites inter)
  float* h3 = inter;
  gemm_f32<1><<<dim3(D_LAT / 64, mblk), b256, 0, stream>>>(emb, W2, h3,
                                                           N_NODES, D_LAT,
                                                           D_EMB);
  // 9. agg3 + elu -> dec_inter (overwrites h1), alpha reused (tied attention)
  float* dec = h1;
  agg_kernel<<<(N_NODES + 3) / 4, b256, 0, stream>>>(h3, rowptr, ssrc, slogit,
                                                     dec);
  // 10. recon = dec @ W1^T [N,256]@[256,512]
  gemm_f32<1><<<dim3(D_IN / 64, mblk), b256, 0, stream>>>(dec, W1, recon,
                                                          N_NODES, D_IN,
                                                          D_LAT);
}

// Round 4
// 508.975 us; speedup vs baseline: 2.1704x; 2.1704x over previous
//
#include <hip/hip_runtime.h>
#include <math.h>

#define N_NODES 50000
#define N_EDGES 800000
#define D_IN 512
#define D_LAT 256
#define D_EMB 64
#define NEG_SLOPE 0.2f

typedef __attribute__((ext_vector_type(8))) short bf16x8;
typedef __attribute__((ext_vector_type(4))) float f32x4;

__device__ __forceinline__ ushort f2b(float f) {
  union { float f; unsigned u; } v; v.f = f;
  return (ushort)((v.u + 0x7fffu + ((v.u >> 16) & 1u)) >> 16);
}
__device__ __forceinline__ float b2f(ushort h) {
  union { unsigned u; float f; } v; v.u = ((unsigned)h) << 16;
  return v.f;
}

__device__ __forceinline__ float wave_reduce_sum(float v) {
#pragma unroll
  for (int off = 32; off > 0; off >>= 1) v += __shfl_xor(v, off, 64);
  return v;
}
__device__ __forceinline__ float wave_reduce_max(float v) {
#pragma unroll
  for (int off = 32; off > 0; off >>= 1) v = fmaxf(v, __shfl_xor(v, off, 64));
  return v;
}

// ---------------------------------------------------------------------------
// bf16 MFMA GEMM: C[M,N] = A[M,K] @ B[N,K]^T   (both row-major bf16)
// BK=32. Wave grid WRxWC, each wave computes (BM/WR)x(BN/WC) via 16x16x32.
// LDS tiles stored row-major [rows][32] (64B rows) -> the fragment read
// pattern (16 rows x 4 k-slots of 16B) exactly tiles 1KB => conflict-free.
// Staged with global_load_lds width 16 (linear LDS dest = tid*16).
// N % BN == 0 and K % 32 == 0 required; M guarded (clamp stage, guard store).
// ---------------------------------------------------------------------------
template <int BM, int BN, int WR, int WC, int WF32, int WBF16>
__global__ __launch_bounds__(WR * WC * 64) void gemm_mfma(
    const ushort* __restrict__ A, const ushort* __restrict__ B,
    float* __restrict__ Cf, ushort* __restrict__ Cb, int M, int N, int K) {
  constexpr int BK = 32;
  constexpr int WTM = BM / WR, WTN = BN / WC;
  constexpr int FM = WTM / 16, FN = WTN / 16;
  constexpr int NT = WR * WC * 64;
  constexpr int AIT = (BM * BK * 2) / (NT * 16);
  constexpr int BIT_ = (BN * BK * 2) / (NT * 16);
  __shared__ ushort As[BM][BK];
  __shared__ ushort Bs[BN][BK];
  const int tid = threadIdx.x, lane = tid & 63, wid = tid >> 6;
  const int wr = wid / WC, wc = wid % WC;
  const int bm = blockIdx.y * BM, bn = blockIdx.x * BN;
  f32x4 acc[FM][FN] = {};

  for (int k0 = 0; k0 < K; k0 += BK) {
#pragma unroll
    for (int it = 0; it < AIT; ++it) {
      int off = it * (NT * 16) + tid * 16;   // byte offset in A tile
      int row = off >> 6;                    // 64 B per row
      int grow = bm + row; grow = grow < M ? grow : (M - 1);
      const ushort* g = A + (size_t)grow * K + k0 + ((off & 63) >> 1);
      __builtin_amdgcn_global_load_lds(
          (const __attribute__((address_space(1))) void*)g,
          (__attribute__((address_space(3))) void*)((char*)&As[0][0] + off),
          16, 0, 0);
    }
#pragma unroll
    for (int it = 0; it < BIT_; ++it) {
      int off = it * (NT * 16) + tid * 16;
      int row = off >> 6;
      const ushort* g = B + (size_t)(bn + row) * K + k0 + ((off & 63) >> 1);
      __builtin_amdgcn_global_load_lds(
          (const __attribute__((address_space(1))) void*)g,
          (__attribute__((address_space(3))) void*)((char*)&Bs[0][0] + off),
          16, 0, 0);
    }
    __syncthreads();
    const int kb = (lane >> 4) * 8, rl = lane & 15;
    bf16x8 af[FM], bfr[FN];
#pragma unroll
    for (int i = 0; i < FM; ++i)
      af[i] = *(const bf16x8*)&As[wr * WTM + i * 16 + rl][kb];
#pragma unroll
    for (int j = 0; j < FN; ++j)
      bfr[j] = *(const bf16x8*)&Bs[wc * WTN + j * 16 + rl][kb];
#pragma unroll
    for (int i = 0; i < FM; ++i)
#pragma unroll
      for (int j = 0; j < FN; ++j)
        acc[i][j] = __builtin_amdgcn_mfma_f32_16x16x32_bf16(af[i], bfr[j],
                                                            acc[i][j], 0, 0, 0);
    __syncthreads();
  }
  // epilogue: C/D layout col=lane&15, row=(lane>>4)*4+reg (m89-verified)
  const int cl = lane & 15, rg = (lane >> 4) * 4;
#pragma unroll
  for (int i = 0; i < FM; ++i)
#pragma unroll
    for (int j = 0; j < FN; ++j)
#pragma unroll
      for (int r = 0; r < 4; ++r) {
        int grow = bm + wr * WTM + i * 16 + rg + r;
        if (grow >= M) continue;
        int gcol = bn + wc * WTN + j * 16 + cl;
        float v = acc[i][j][r];
        if (WF32) Cf[(size_t)grow * N + gcol] = v;
        if (WBF16) Cb[(size_t)grow * N + gcol] = f2b(v);
      }
}

// f32 -> bf16, vectorized (float4 in, ushort4 out), grid-stride
__global__ __launch_bounds__(256) void conv_f32_bf16(
    const float* __restrict__ in, ushort* __restrict__ out, int n4) {
  int stride = gridDim.x * blockDim.x;
  for (int i = blockIdx.x * blockDim.x + threadIdx.x; i < n4; i += stride) {
    float4 v = ((const float4*)in)[i];
    ushort4 o;
    o.x = f2b(v.x); o.y = f2b(v.y); o.z = f2b(v.z); o.w = f2b(v.w);
    ((ushort4*)out)[i] = o;
  }
}

// weights: W1[512,256] -> W1b + W1tb[256,512]; W2[256,64] -> W2b + W2tb[64,256]
__global__ __launch_bounds__(256) void conv_weights(
    const float* __restrict__ W1, const float* __restrict__ W2,
    ushort* __restrict__ W1b, ushort* __restrict__ W1tb,
    ushort* __restrict__ W2b, ushort* __restrict__ W2tb) {
  int i = blockIdx.x * blockDim.x + threadIdx.x;
  if (i < D_IN * D_LAT) {
    ushort b = f2b(W1[i]);
    int r = i / D_LAT, c = i % D_LAT;
    W1b[i] = b;
    W1tb[(size_t)c * D_IN + r] = b;
  }
  if (i < D_LAT * D_EMB) {
    ushort b = f2b(W2[i]);
    int r = i / D_EMB, c = i % D_EMB;
    W2b[i] = b;
    W2tb[(size_t)c * D_LAT + r] = b;
  }
}

// als[i] = h1[i]·a_src, ald[i] = h1[i]·a_dst  (f32 h1, one wave per node)
__global__ __launch_bounds__(256) void node_logits(
    const float* __restrict__ h1, const float* __restrict__ a_src,
    const float* __restrict__ a_dst, float* __restrict__ als,
    float* __restrict__ ald) {
  int wave = threadIdx.x >> 6, lane = threadIdx.x & 63;
  int node = blockIdx.x * 4 + wave;
  if (node >= N_NODES) return;
  float4 h = *(const float4*)(h1 + (size_t)node * D_LAT + lane * 4);
  float4 as4 = *(const float4*)(a_src + lane * 4);
  float4 ad4 = *(const float4*)(a_dst + lane * 4);
  float s = h.x * as4.x + h.y * as4.y + h.z * as4.z + h.w * as4.w;
  float d = h.x * ad4.x + h.y * ad4.y + h.z * ad4.z + h.w * ad4.w;
  s = wave_reduce_sum(s);
  d = wave_reduce_sum(d);
  if (lane == 0) { als[node] = s; ald[node] = d; }
}

__global__ void hist_kernel(const int* __restrict__ dst,
                            int* __restrict__ counts) {
  int e = blockIdx.x * blockDim.x + threadIdx.x;
  if (e < N_EDGES) atomicAdd(&counts[dst[e]], 1);
}

__global__ __launch_bounds__(1024) void scan_kernel(
    const int* __restrict__ counts, int* __restrict__ rowptr) {
  __shared__ int part[1024];
  const int n = N_NODES;
  int tid = threadIdx.x;
  const int per = (n + 1023) / 1024;
  int base = tid * per;
  int sum = 0;
  for (int i = 0; i < per; i++) {
    int idx = base + i;
    if (idx < n) sum += counts[idx];
  }
  part[tid] = sum;
  __syncthreads();
  for (int off = 1; off < 1024; off <<= 1) {
    int v = (tid >= off) ? part[tid - off] : 0;
    __syncthreads();
    part[tid] += v;
    __syncthreads();
  }
  int run = (tid == 0) ? 0 : part[tid - 1];
  for (int i = 0; i < per; i++) {
    int idx = base + i;
    if (idx < n) { rowptr[idx] = run; run += counts[idx]; }
  }
  if (tid == 0) rowptr[n] = part[1023];
}

__global__ void scatter_kernel(const int* __restrict__ src,
                               const int* __restrict__ dst,
                               const float* __restrict__ als,
                               const float* __restrict__ ald,
                               const int* __restrict__ rowptr,
                               int* __restrict__ fill, int* __restrict__ ssrc,
                               float* __restrict__ slogit) {
  int e = blockIdx.x * blockDim.x + threadIdx.x;
  if (e >= N_EDGES) return;
  int s = src[e], d = dst[e];
  int pos = rowptr[d] + atomicAdd(&fill[d], 1);
  float x = als[s] + ald[d];
  slogit[pos] = (x > 0.f) ? x : NEG_SLOPE * x;
  ssrc[pos] = s;
}

// segment softmax in place: slogit -> normalized alpha. One wave per node.
__global__ __launch_bounds__(256) void alpha_kernel(
    const int* __restrict__ rowptr, float* __restrict__ slogit) {
  int wave = threadIdx.x >> 6, lane = threadIdx.x & 63;
  int node = blockIdx.x * 4 + wave;
  if (node >= N_NODES) return;
  int beg = rowptr[node], end = rowptr[node + 1];
  float m = -INFINITY;
  for (int e = beg + lane; e < end; e += 64) m = fmaxf(m, slogit[e]);
  m = wave_reduce_max(m);
  float s = 0.f;
  for (int e = beg + lane; e < end; e += 64) s += __expf(slogit[e] - m);
  s = wave_reduce_sum(s);
  float inv = (s > 0.f) ? 1.f / s : 0.f;
  for (int e = beg + lane; e < end; e += 64)
    slogit[e] = __expf(slogit[e] - m) * inv;
}

// weighted gather + ELU, bf16 features. One wave per node, lane owns 4 dims.
__global__ __launch_bounds__(256) void agg_bf16(
    const ushort* __restrict__ feat, const int* __restrict__ rowptr,
    const int* __restrict__ ssrc, const float* __restrict__ alpha,
    ushort* __restrict__ out) {
  int wave = threadIdx.x >> 6, lane = threadIdx.x & 63;
  int node = blockIdx.x * 4 + wave;
  if (node >= N_NODES) return;
  int beg = rowptr[node], end = rowptr[node + 1];
  float a0 = 0.f, a1 = 0.f, a2 = 0.f, a3 = 0.f;
  for (int e = beg; e < end; ++e) {
    float a = alpha[e];
    int s = ssrc[e];
    ushort4 h = *(const ushort4*)(feat + (size_t)s * D_LAT + lane * 4);
    a0 += a * b2f(h.x); a1 += a * b2f(h.y);
    a2 += a * b2f(h.z); a3 += a * b2f(h.w);
  }
  ushort4 o;
  o.x = f2b(a0 > 0.f ? a0 : __expf(a0) - 1.f);
  o.y = f2b(a1 > 0.f ? a1 : __expf(a1) - 1.f);
  o.z = f2b(a2 > 0.f ? a2 : __expf(a2) - 1.f);
  o.w = f2b(a3 > 0.f ? a3 : __expf(a3) - 1.f);
  *(ushort4*)(out + (size_t)node * D_LAT + lane * 4) = o;
}

extern "C" void kernel_launch(void* const* d_in, const int* in_sizes, int n_in,
                              void* d_out, int out_size, void* d_ws,
                              size_t ws_size, hipStream_t stream) {
  const float* x = (const float*)d_in[0];
  const float* W1 = (const float*)d_in[1];
  const float* a1s = (const float*)d_in[2];
  const float* a1d = (const float*)d_in[3];
  const float* W2 = (const float*)d_in[4];
  const int* ge = (const int*)d_in[5];
  const int* esrc = ge;
  const int* edst = ge + N_EDGES;

  float* out = (float*)d_out;
  float* emb = out;                              // [N, 64]
  float* recon = out + (size_t)N_NODES * D_EMB;  // [N, 512] (102.4 MB)
  // use the recon region as scratch until GEMM4 overwrites it:
  ushort* xb = (ushort*)recon;                               // 51.2 MB
  float* h1f = (float*)((char*)recon + (size_t)N_NODES * D_IN * 2);  // 51.2 MB

  char* w = (char*)d_ws;
  ushort* h1b = (ushort*)w;    w += (size_t)N_NODES * D_LAT * 2;  // 25.6 MB, reused as decb
  ushort* interb = (ushort*)w; w += (size_t)N_NODES * D_LAT * 2;  // 25.6 MB, reused as h3b
  ushort* embb = (ushort*)w;   w += (size_t)N_NODES * D_EMB * 2;  // 6.4 MB
  ushort* W1b = (ushort*)w;    w += (size_t)D_IN * D_LAT * 2;
  ushort* W1tb = (ushort*)w;   w += (size_t)D_LAT * D_IN * 2;
  ushort* W2b = (ushort*)w;    w += (size_t)D_LAT * D_EMB * 2;
  ushort* W2tb = (ushort*)w;   w += (size_t)D_EMB * D_LAT * 2;
  float* als = (float*)w;      w += (size_t)N_NODES * 4;
  float* ald = (float*)w;      w += (size_t)N_NODES * 4;
  int* counts = (int*)w;       w += (size_t)N_NODES * 4;
  int* rowptr = (int*)w;       w += (size_t)(N_NODES + 4) * 4;
  int* fill = (int*)w;         w += (size_t)N_NODES * 4;
  int* ssrc = (int*)w;         w += (size_t)N_EDGES * 4;
  float* slogit = (float*)w;   w += (size_t)N_EDGES * 4;

  hipMemsetAsync(counts, 0, N_NODES * 4, stream);
  hipMemsetAsync(fill, 0, N_NODES * 4, stream);

  dim3 b256(256);
  const int MB = (N_NODES + 127) / 128;  // 391

  // 0. conversions
  conv_f32_bf16<<<2048, b256, 0, stream>>>(x, xb, N_NODES * D_IN / 4);
  conv_weights<<<(D_IN * D_LAT + 255) / 256, b256, 0, stream>>>(
      W1, W2, W1b, W1tb, W2b, W2tb);

  // 1. h1 = x @ W1  -> h1f (f32, for logits) + h1b (bf16, for gather)
  gemm_mfma<128, 128, 2, 2, 1, 1><<<dim3(D_LAT / 128, MB), b256, 0, stream>>>(
      xb, W1tb, h1f, h1b, N_NODES, D_LAT, D_IN);
  // 2. per-node attention logits
  node_logits<<<(N_NODES + 3) / 4, b256, 0, stream>>>(h1f, a1s, a1d, als, ald);
  // 3-5. CSR by dst + leaky-relu logits
  hist_kernel<<<(N_EDGES + 255) / 256, b256, 0, stream>>>(edst, counts);
  scan_kernel<<<1, 1024, 0, stream>>>(counts, rowptr);
  scatter_kernel<<<(N_EDGES + 255) / 256, b256, 0, stream>>>(
      esrc, edst, als, ald, rowptr, fill, ssrc, slogit);
  // 6. normalized alpha in place (shared by both agg passes — tied attention)
  alpha_kernel<<<(N_NODES + 3) / 4, b256, 0, stream>>>(rowptr, slogit);
  // 7. inter = elu(sum alpha * h1[src])
  agg_bf16<<<(N_NODES + 3) / 4, b256, 0, stream>>>(h1b, rowptr, ssrc, slogit,
                                                   interb);
  // 8. emb = inter @ W2 (f32 to d_out + bf16 copy)
  gemm_mfma<128, 64, 2, 2, 1, 1><<<dim3(1, MB), b256, 0, stream>>>(
      interb, W2tb, emb, embb, N_NODES, D_EMB, D_LAT);
  // 9. h3 = emb @ W2^T (bf16) — reuse interb
  ushort* h3b = interb;
  gemm_mfma<128, 128, 2, 2, 0, 1><<<dim3(D_LAT / 128, MB), b256, 0, stream>>>(
      embb, W2b, (float*)nullptr, h3b, N_NODES, D_LAT, D_EMB);
  // 10. dec = elu(sum alpha * h3[src]) — reuse h1b
  ushort* decb = h1b;
  agg_bf16<<<(N_NODES + 3) / 4, b256, 0, stream>>>(h3b, rowptr, ssrc, slogit,
                                                   decb);
  // 11. recon = dec @ W1^T (f32 to d_out; overwrites xb/h1f scratch)
  gemm_mfma<128, 128, 2, 2, 1, 0><<<dim3(D_IN / 128, MB), b256, 0, stream>>>(
      decb, W1b, recon, (ushort*)nullptr, N_NODES, D_IN, D_LAT);
}

// Round 5
// 352.168 us; speedup vs baseline: 3.1368x; 1.4453x over previous
//
#include <hip/hip_runtime.h>
#include <math.h>

#define N_NODES 50000
#define N_EDGES 800000
#define D_IN 512
#define D_LAT 256
#define D_EMB 64
#define NEG_SLOPE 0.2f

typedef __attribute__((ext_vector_type(8))) short bf16x8;
typedef __attribute__((ext_vector_type(8))) unsigned short u16x8;
typedef __attribute__((ext_vector_type(4))) float f32x4;

__device__ __forceinline__ ushort f2b(float f) {
  union { float f; unsigned u; } v; v.f = f;
  return (ushort)((v.u + 0x7fffu + ((v.u >> 16) & 1u)) >> 16);
}
__device__ __forceinline__ float b2f(ushort h) {
  union { unsigned u; float f; } v; v.u = ((unsigned)h) << 16;
  return v.f;
}

__device__ __forceinline__ float wave_reduce_sum(float v) {
#pragma unroll
  for (int off = 32; off > 0; off >>= 1) v += __shfl_xor(v, off, 64);
  return v;
}
__device__ __forceinline__ float wave_reduce_max(float v) {
#pragma unroll
  for (int off = 32; off > 0; off >>= 1) v = fmaxf(v, __shfl_xor(v, off, 64));
  return v;
}

// ---------------------------------------------------------------------------
// bf16 MFMA GEMM: C[M,N] = A[M,K] @ B[N,K]^T  (row-major).
// AF32=1: A is f32, staged via regs + cvt + ds_write_b128 (same linear LDS
// layout as global_load_lds dest). AF32=0: A bf16 via global_load_lds w16.
// LDS tiles [rows][32] (64B rows): fragment reads tile 1KB conflict-free.
// ---------------------------------------------------------------------------
template <int BM, int BN, int WR, int WC, int AF32, int WF32, int WBF16>
__global__ __launch_bounds__(WR * WC * 64) void gemm_mfma(
    const void* __restrict__ Aptr, const ushort* __restrict__ B,
    float* __restrict__ Cf, ushort* __restrict__ Cb, int M, int N, int K) {
  constexpr int BK = 32;
  constexpr int WTM = BM / WR, WTN = BN / WC;
  constexpr int FM = WTM / 16, FN = WTN / 16;
  constexpr int NT = WR * WC * 64;
  constexpr int AIT = (BM * BK * 2) / (NT * 16);
  constexpr int BIT_ = (BN * BK * 2) / (NT * 16);
  __shared__ ushort As[BM][BK];
  __shared__ ushort Bs[BN][BK];
  const int tid = threadIdx.x, lane = tid & 63, wid = tid >> 6;
  const int wr = wid / WC, wc = wid % WC;
  const int bm = blockIdx.y * BM, bn = blockIdx.x * BN;
  f32x4 acc[FM][FN] = {};

  for (int k0 = 0; k0 < K; k0 += BK) {
    if constexpr (AF32) {
      const float* Af = (const float*)Aptr;
#pragma unroll
      for (int it = 0; it < AIT; ++it) {
        int off = it * (NT * 16) + tid * 16;  // byte offset in bf16 tile
        int row = off >> 6;                   // 64 B per LDS row
        int ecol = (off & 63) >> 1;           // element col 0..31 (x8)
        int grow = bm + row; grow = grow < M ? grow : (M - 1);
        const float* g = Af + (size_t)grow * K + k0 + ecol;
        float4 f0 = *(const float4*)g;
        float4 f1 = *(const float4*)(g + 4);
        u16x8 hb;
        hb[0] = f2b(f0.x); hb[1] = f2b(f0.y); hb[2] = f2b(f0.z); hb[3] = f2b(f0.w);
        hb[4] = f2b(f1.x); hb[5] = f2b(f1.y); hb[6] = f2b(f1.z); hb[7] = f2b(f1.w);
        *(u16x8*)((char*)&As[0][0] + off) = hb;
      }
    } else {
      const ushort* Ab = (const ushort*)Aptr;
#pragma unroll
      for (int it = 0; it < AIT; ++it) {
        int off = it * (NT * 16) + tid * 16;
        int row = off >> 6;
        int grow = bm + row; grow = grow < M ? grow : (M - 1);
        const ushort* g = Ab + (size_t)grow * K + k0 + ((off & 63) >> 1);
        __builtin_amdgcn_global_load_lds(
            (const __attribute__((address_space(1))) void*)g,
            (__attribute__((address_space(3))) void*)((char*)&As[0][0] + off),
            16, 0, 0);
      }
    }
#pragma unroll
    for (int it = 0; it < BIT_; ++it) {
      int off = it * (NT * 16) + tid * 16;
      int row = off >> 6;
      const ushort* g = B + (size_t)(bn + row) * K + k0 + ((off & 63) >> 1);
      __builtin_amdgcn_global_load_lds(
          (const __attribute__((address_space(1))) void*)g,
          (__attribute__((address_space(3))) void*)((char*)&Bs[0][0] + off),
          16, 0, 0);
    }
    __syncthreads();
    const int kb = (lane >> 4) * 8, rl = lane & 15;
    bf16x8 af[FM], bfr[FN];
#pragma unroll
    for (int i = 0; i < FM; ++i)
      af[i] = *(const bf16x8*)&As[wr * WTM + i * 16 + rl][kb];
#pragma unroll
    for (int j = 0; j < FN; ++j)
      bfr[j] = *(const bf16x8*)&Bs[wc * WTN + j * 16 + rl][kb];
#pragma unroll
    for (int i = 0; i < FM; ++i)
#pragma unroll
      for (int j = 0; j < FN; ++j)
        acc[i][j] = __builtin_amdgcn_mfma_f32_16x16x32_bf16(af[i], bfr[j],
                                                            acc[i][j], 0, 0, 0);
    __syncthreads();
  }
  // epilogue: C/D layout col=lane&15, row=(lane>>4)*4+reg (m89-verified)
  const int cl = lane & 15, rg = (lane >> 4) * 4;
#pragma unroll
  for (int i = 0; i < FM; ++i)
#pragma unroll
    for (int j = 0; j < FN; ++j)
#pragma unroll
      for (int r = 0; r < 4; ++r) {
        int grow = bm + wr * WTM + i * 16 + rg + r;
        if (grow >= M) continue;
        int gcol = bn + wc * WTN + j * 16 + cl;
        float v = acc[i][j][r];
        if (WF32) Cf[(size_t)grow * N + gcol] = v;
        if (WBF16) Cb[(size_t)grow * N + gcol] = f2b(v);
      }
}

// weights: W1[512,256] -> W1b + W1tb[256,512]; W2[256,64] -> W2b + W2tb[64,256]
__global__ __launch_bounds__(256) void conv_weights(
    const float* __restrict__ W1, const float* __restrict__ W2,
    ushort* __restrict__ W1b, ushort* __restrict__ W1tb,
    ushort* __restrict__ W2b, ushort* __restrict__ W2tb) {
  int i = blockIdx.x * blockDim.x + threadIdx.x;
  if (i < D_IN * D_LAT) {
    ushort b = f2b(W1[i]);
    int r = i / D_LAT, c = i % D_LAT;
    W1b[i] = b;
    W1tb[(size_t)c * D_IN + r] = b;
  }
  if (i < D_LAT * D_EMB) {
    ushort b = f2b(W2[i]);
    int r = i / D_EMB, c = i % D_EMB;
    W2b[i] = b;
    W2tb[(size_t)c * D_LAT + r] = b;
  }
}

// als[i] = h1[i]·a_src, ald[i] = h1[i]·a_dst  (bf16 h1, one wave per node)
__global__ __launch_bounds__(256) void node_logits_b(
    const ushort* __restrict__ h1b, const float* __restrict__ a_src,
    const float* __restrict__ a_dst, float* __restrict__ als,
    float* __restrict__ ald) {
  int wave = threadIdx.x >> 6, lane = threadIdx.x & 63;
  int node = blockIdx.x * 4 + wave;
  if (node >= N_NODES) return;
  ushort4 h = *(const ushort4*)(h1b + (size_t)node * D_LAT + lane * 4);
  float4 as4 = *(const float4*)(a_src + lane * 4);
  float4 ad4 = *(const float4*)(a_dst + lane * 4);
  float hx = b2f(h.x), hy = b2f(h.y), hz = b2f(h.z), hw = b2f(h.w);
  float s = hx * as4.x + hy * as4.y + hz * as4.z + hw * as4.w;
  float d = hx * ad4.x + hy * ad4.y + hz * ad4.z + hw * ad4.w;
  s = wave_reduce_sum(s);
  d = wave_reduce_sum(d);
  if (lane == 0) { als[node] = s; ald[node] = d; }
}

__global__ void hist_kernel(const int* __restrict__ dst,
                            int* __restrict__ counts) {
  int e = blockIdx.x * blockDim.x + threadIdx.x;
  if (e < N_EDGES) atomicAdd(&counts[dst[e]], 1);
}

// --------- hierarchical exclusive scan: counts[N] -> rowptr[N+1] ----------
#define SCAN_NBLK ((N_NODES + 511) / 512)

__global__ __launch_bounds__(512) void scan_phase1(
    const int* __restrict__ counts, int* __restrict__ rowptr,
    int* __restrict__ bsum) {
  __shared__ int wsum[9];
  int idx = blockIdx.x * 512 + threadIdx.x;
  int lane = threadIdx.x & 63, wv = threadIdx.x >> 6;
  int c = (idx < N_NODES) ? counts[idx] : 0;
  int v = c;
#pragma unroll
  for (int off = 1; off < 64; off <<= 1) {
    int t = __shfl_up(v, off, 64);
    if (lane >= off) v += t;
  }
  if (lane == 63) wsum[wv] = v;
  __syncthreads();
  if (threadIdx.x == 0) {
    int r = 0;
    for (int i = 0; i < 8; i++) { int t = wsum[i]; wsum[i] = r; r += t; }
    bsum[blockIdx.x] = r;
  }
  __syncthreads();
  if (idx < N_NODES) rowptr[idx] = wsum[wv] + v - c;  // block-local exclusive
}

__global__ __launch_bounds__(128) void scan_phase2(int* __restrict__ bsum) {
  __shared__ int s[128];
  int tid = threadIdx.x;
  int v = (tid < SCAN_NBLK) ? bsum[tid] : 0;
  s[tid] = v;
  __syncthreads();
  for (int off = 1; off < 128; off <<= 1) {
    int t = (tid >= off) ? s[tid - off] : 0;
    __syncthreads();
    s[tid] += t;
    __syncthreads();
  }
  if (tid < SCAN_NBLK) bsum[tid] = s[tid] - v;  // exclusive
}

__global__ __launch_bounds__(512) void scan_phase3(
    int* __restrict__ rowptr, const int* __restrict__ bsum,
    const int* __restrict__ counts) {
  int idx = blockIdx.x * 512 + threadIdx.x;
  if (idx < N_NODES) {
    int r = rowptr[idx] + bsum[blockIdx.x];
    rowptr[idx] = r;
    if (idx == N_NODES - 1) rowptr[N_NODES] = r + counts[idx];
  }
}

__global__ void scatter_kernel(const int* __restrict__ src,
                               const int* __restrict__ dst,
                               const float* __restrict__ als,
                               const float* __restrict__ ald,
                               const int* __restrict__ rowptr,
                               int* __restrict__ fill, int* __restrict__ ssrc,
                               float* __restrict__ slogit) {
  int e = blockIdx.x * blockDim.x + threadIdx.x;
  if (e >= N_EDGES) return;
  int s = src[e], d = dst[e];
  int pos = rowptr[d] + atomicAdd(&fill[d], 1);
  float x = als[s] + ald[d];
  slogit[pos] = (x > 0.f) ? x : NEG_SLOPE * x;
  ssrc[pos] = s;
}

// segment softmax in place: slogit -> normalized alpha. One wave per node.
__global__ __launch_bounds__(256) void alpha_kernel(
    const int* __restrict__ rowptr, float* __restrict__ slogit) {
  int wave = threadIdx.x >> 6, lane = threadIdx.x & 63;
  int node = blockIdx.x * 4 + wave;
  if (node >= N_NODES) return;
  int beg = rowptr[node], end = rowptr[node + 1];
  float m = -INFINITY;
  for (int e = beg + lane; e < end; e += 64) m = fmaxf(m, slogit[e]);
  m = wave_reduce_max(m);
  float s = 0.f;
  for (int e = beg + lane; e < end; e += 64) s += __expf(slogit[e] - m);
  s = wave_reduce_sum(s);
  float inv = (s > 0.f) ? 1.f / s : 0.f;
  for (int e = beg + lane; e < end; e += 64)
    slogit[e] = __expf(slogit[e] - m) * inv;
}

// weighted gather + ELU. One wave per node; half-waves process alternate
// edges; 32 lanes x ushort8 = one full 512B feature row per half per edge.
__global__ __launch_bounds__(256) void agg_bf16(
    const ushort* __restrict__ feat, const int* __restrict__ rowptr,
    const int* __restrict__ ssrc, const float* __restrict__ alpha,
    ushort* __restrict__ out) {
  int wave = threadIdx.x >> 6, lane = threadIdx.x & 63;
  int node = blockIdx.x * 4 + wave;
  if (node >= N_NODES) return;
  int beg = rowptr[node], end = rowptr[node + 1];
  int half = lane >> 5, hl = lane & 31;
  float acc[8] = {};
  int e = beg + half;
  for (; e + 2 < end; e += 4) {  // 2 edges per half in flight
    float a0 = alpha[e];
    int s0 = ssrc[e];
    float a1 = alpha[e + 2];
    int s1 = ssrc[e + 2];
    u16x8 h0 = *(const u16x8*)(feat + (size_t)s0 * D_LAT + hl * 8);
    u16x8 h1 = *(const u16x8*)(feat + (size_t)s1 * D_LAT + hl * 8);
#pragma unroll
    for (int q = 0; q < 8; q++) acc[q] += a0 * b2f(h0[q]);
#pragma unroll
    for (int q = 0; q < 8; q++) acc[q] += a1 * b2f(h1[q]);
  }
  for (; e < end; e += 2) {
    float a = alpha[e];
    int s = ssrc[e];
    u16x8 h = *(const u16x8*)(feat + (size_t)s * D_LAT + hl * 8);
#pragma unroll
    for (int q = 0; q < 8; q++) acc[q] += a * b2f(h[q]);
  }
#pragma unroll
  for (int q = 0; q < 8; q++) acc[q] += __shfl_xor(acc[q], 32, 64);
  if (half == 0) {
    u16x8 o;
#pragma unroll
    for (int q = 0; q < 8; q++) {
      float v = acc[q];
      o[q] = f2b(v > 0.f ? v : __expf(v) - 1.f);
    }
    *(u16x8*)(out + (size_t)node * D_LAT + hl * 8) = o;
  }
}

extern "C" void kernel_launch(void* const* d_in, const int* in_sizes, int n_in,
                              void* d_out, int out_size, void* d_ws,
                              size_t ws_size, hipStream_t stream) {
  const float* x = (const float*)d_in[0];
  const float* W1 = (const float*)d_in[1];
  const float* a1s = (const float*)d_in[2];
  const float* a1d = (const float*)d_in[3];
  const float* W2 = (const float*)d_in[4];
  const int* ge = (const int*)d_in[5];
  const int* esrc = ge;
  const int* edst = ge + N_EDGES;

  float* out = (float*)d_out;
  float* emb = out;                              // [N, 64]
  float* recon = out + (size_t)N_NODES * D_EMB;  // [N, 512]

  char* w = (char*)d_ws;
  ushort* h1b = (ushort*)w;    w += (size_t)N_NODES * D_LAT * 2;  // reused as decb
  ushort* interb = (ushort*)w; w += (size_t)N_NODES * D_LAT * 2;  // reused as h3b
  ushort* embb = (ushort*)w;   w += (size_t)N_NODES * D_EMB * 2;
  ushort* W1b = (ushort*)w;    w += (size_t)D_IN * D_LAT * 2;
  ushort* W1tb = (ushort*)w;   w += (size_t)D_LAT * D_IN * 2;
  ushort* W2b = (ushort*)w;    w += (size_t)D_LAT * D_EMB * 2;
  ushort* W2tb = (ushort*)w;   w += (size_t)D_EMB * D_LAT * 2;
  float* als = (float*)w;      w += (size_t)N_NODES * 4;
  float* ald = (float*)w;      w += (size_t)N_NODES * 4;
  int* counts = (int*)w;       w += (size_t)N_NODES * 4;
  int* rowptr = (int*)w;       w += (size_t)(N_NODES + 4) * 4;
  int* fill = (int*)w;         w += (size_t)N_NODES * 4;
  int* bsum = (int*)w;         w += 128 * 4;
  int* ssrc = (int*)w;         w += (size_t)N_EDGES * 4;
  float* slogit = (float*)w;   w += (size_t)N_EDGES * 4;

  hipMemsetAsync(counts, 0, N_NODES * 4, stream);
  hipMemsetAsync(fill, 0, N_NODES * 4, stream);

  dim3 b256(256);
  const int MB = (N_NODES + 127) / 128;  // 391

  // 0. weight conversions (x converted inline in GEMM1)
  conv_weights<<<(D_IN * D_LAT + 255) / 256, b256, 0, stream>>>(
      W1, W2, W1b, W1tb, W2b, W2tb);

  // 1. h1 = x @ W1 (A f32 staged inline) -> h1b bf16
  gemm_mfma<128, 128, 2, 2, 1, 0, 1><<<dim3(D_LAT / 128, MB), b256, 0, stream>>>(
      x, W1tb, (float*)nullptr, h1b, N_NODES, D_LAT, D_IN);
  // 2. per-node attention logits from bf16 h1
  node_logits_b<<<(N_NODES + 3) / 4, b256, 0, stream>>>(h1b, a1s, a1d, als, ald);
  // 3-5. CSR by dst (hist + hierarchical scan + scatter)
  hist_kernel<<<(N_EDGES + 255) / 256, b256, 0, stream>>>(edst, counts);
  scan_phase1<<<SCAN_NBLK, 512, 0, stream>>>(counts, rowptr, bsum);
  scan_phase2<<<1, 128, 0, stream>>>(bsum);
  scan_phase3<<<SCAN_NBLK, 512, 0, stream>>>(rowptr, bsum, counts);
  scatter_kernel<<<(N_EDGES + 255) / 256, b256, 0, stream>>>(
      esrc, edst, als, ald, rowptr, fill, ssrc, slogit);
  // 6. normalized alpha in place (tied attention -> shared by both aggs)
  alpha_kernel<<<(N_NODES + 3) / 4, b256, 0, stream>>>(rowptr, slogit);
  // 7. inter = elu(sum alpha * h1[src])
  agg_bf16<<<(N_NODES + 3) / 4, b256, 0, stream>>>(h1b, rowptr, ssrc, slogit,
                                                   interb);
  // 8. emb = inter @ W2 (f32 to d_out + bf16 copy)
  gemm_mfma<128, 64, 2, 2, 0, 1, 1><<<dim3(1, MB), b256, 0, stream>>>(
      interb, W2tb, emb, embb, N_NODES, D_EMB, D_LAT);
  // 9. h3 = emb @ W2^T (bf16) — reuse interb
  ushort* h3b = interb;
  gemm_mfma<128, 128, 2, 2, 0, 0, 1><<<dim3(D_LAT / 128, MB), b256, 0, stream>>>(
      embb, W2b, (float*)nullptr, h3b, N_NODES, D_LAT, D_EMB);
  // 10. dec = elu(sum alpha * h3[src]) — reuse h1b
  ushort* decb = h1b;
  agg_bf16<<<(N_NODES + 3) / 4, b256, 0, stream>>>(h3b, rowptr, ssrc, slogit,
                                                   decb);
  // 11. recon = dec @ W1^T (f32 to d_out)
  gemm_mfma<128, 128, 2, 2, 0, 1, 0><<<dim3(D_IN / 128, MB), b256, 0, stream>>>(
      decb, W1b, recon, (ushort*)nullptr, N_NODES, D_IN, D_LAT);
}

// Round 6
// 302.492 us; speedup vs baseline: 3.6520x; 1.1642x over previous
//
#include <hip/hip_runtime.h>
#include <math.h>

#define N_NODES 50000
#define N_EDGES 800000
#define D_IN 512
#define D_LAT 256
#define D_EMB 64
#define NEG_SLOPE 0.2f

typedef __attribute__((ext_vector_type(8))) short bf16x8;
typedef __attribute__((ext_vector_type(8))) unsigned short u16x8;
typedef __attribute__((ext_vector_type(4))) float f32x4;

__device__ __forceinline__ ushort f2b(float f) {
  union { float f; unsigned u; } v; v.f = f;
  return (ushort)((v.u + 0x7fffu + ((v.u >> 16) & 1u)) >> 16);
}
__device__ __forceinline__ float b2f(ushort h) {
  union { unsigned u; float f; } v; v.u = ((unsigned)h) << 16;
  return v.f;
}

__device__ __forceinline__ float wave_reduce_sum(float v) {
#pragma unroll
  for (int off = 32; off > 0; off >>= 1) v += __shfl_xor(v, off, 64);
  return v;
}
__device__ __forceinline__ float wave_reduce_max(float v) {
#pragma unroll
  for (int off = 32; off > 0; off >>= 1) v = fmaxf(v, __shfl_xor(v, off, 64));
  return v;
}

// ---------------------------------------------------------------------------
// bf16 MFMA GEMM: C[M,N] = A[M,K] @ B[N,K]^T  (row-major).
// AF32=1: A is f32, staged via regs + cvt + ds_write_b128 (same linear LDS
// layout as global_load_lds dest). AF32=0: A bf16 via global_load_lds w16.
// ELU=1: apply elu to the result before store.
// LDS tiles [rows][32] (64B rows): fragment reads tile 1KB.
// ---------------------------------------------------------------------------
template <int BM, int BN, int WR, int WC, int AF32, int WF32, int WBF16,
          int ELU>
__global__ __launch_bounds__(WR * WC * 64) void gemm_mfma(
    const void* __restrict__ Aptr, const ushort* __restrict__ B,
    float* __restrict__ Cf, ushort* __restrict__ Cb, int M, int N, int K) {
  constexpr int BK = 32;
  constexpr int WTM = BM / WR, WTN = BN / WC;
  constexpr int FM = WTM / 16, FN = WTN / 16;
  constexpr int NT = WR * WC * 64;
  constexpr int AIT = (BM * BK * 2) / (NT * 16);
  constexpr int BIT_ = (BN * BK * 2) / (NT * 16);
  __shared__ ushort As[BM][BK];
  __shared__ ushort Bs[BN][BK];
  const int tid = threadIdx.x, lane = tid & 63, wid = tid >> 6;
  const int wr = wid / WC, wc = wid % WC;
  const int bm = blockIdx.y * BM, bn = blockIdx.x * BN;
  f32x4 acc[FM][FN] = {};

  for (int k0 = 0; k0 < K; k0 += BK) {
    if constexpr (AF32) {
      const float* Af = (const float*)Aptr;
#pragma unroll
      for (int it = 0; it < AIT; ++it) {
        int off = it * (NT * 16) + tid * 16;  // byte offset in bf16 tile
        int row = off >> 6;                   // 64 B per LDS row
        int ecol = (off & 63) >> 1;           // element col (x8)
        int grow = bm + row; grow = grow < M ? grow : (M - 1);
        const float* g = Af + (size_t)grow * K + k0 + ecol;
        float4 f0 = *(const float4*)g;
        float4 f1 = *(const float4*)(g + 4);
        u16x8 hb;
        hb[0] = f2b(f0.x); hb[1] = f2b(f0.y); hb[2] = f2b(f0.z); hb[3] = f2b(f0.w);
        hb[4] = f2b(f1.x); hb[5] = f2b(f1.y); hb[6] = f2b(f1.z); hb[7] = f2b(f1.w);
        *(u16x8*)((char*)&As[0][0] + off) = hb;
      }
    } else {
      const ushort* Ab = (const ushort*)Aptr;
#pragma unroll
      for (int it = 0; it < AIT; ++it) {
        int off = it * (NT * 16) + tid * 16;
        int row = off >> 6;
        int grow = bm + row; grow = grow < M ? grow : (M - 1);
        const ushort* g = Ab + (size_t)grow * K + k0 + ((off & 63) >> 1);
        __builtin_amdgcn_global_load_lds(
            (const __attribute__((address_space(1))) void*)g,
            (__attribute__((address_space(3))) void*)((char*)&As[0][0] + off),
            16, 0, 0);
      }
    }
#pragma unroll
    for (int it = 0; it < BIT_; ++it) {
      int off = it * (NT * 16) + tid * 16;
      int row = off >> 6;
      const ushort* g = B + (size_t)(bn + row) * K + k0 + ((off & 63) >> 1);
      __builtin_amdgcn_global_load_lds(
          (const __attribute__((address_space(1))) void*)g,
          (__attribute__((address_space(3))) void*)((char*)&Bs[0][0] + off),
          16, 0, 0);
    }
    __syncthreads();
    const int kb = (lane >> 4) * 8, rl = lane & 15;
    bf16x8 af[FM], bfr[FN];
#pragma unroll
    for (int i = 0; i < FM; ++i)
      af[i] = *(const bf16x8*)&As[wr * WTM + i * 16 + rl][kb];
#pragma unroll
    for (int j = 0; j < FN; ++j)
      bfr[j] = *(const bf16x8*)&Bs[wc * WTN + j * 16 + rl][kb];
#pragma unroll
    for (int i = 0; i < FM; ++i)
#pragma unroll
      for (int j = 0; j < FN; ++j)
        acc[i][j] = __builtin_amdgcn_mfma_f32_16x16x32_bf16(af[i], bfr[j],
                                                            acc[i][j], 0, 0, 0);
    __syncthreads();
  }
  // epilogue: C/D layout col=lane&15, row=(lane>>4)*4+reg (m89-verified)
  const int cl = lane & 15, rg = (lane >> 4) * 4;
#pragma unroll
  for (int i = 0; i < FM; ++i)
#pragma unroll
    for (int j = 0; j < FN; ++j)
#pragma unroll
      for (int r = 0; r < 4; ++r) {
        int grow = bm + wr * WTM + i * 16 + rg + r;
        if (grow >= M) continue;
        int gcol = bn + wc * WTN + j * 16 + cl;
        float v = acc[i][j][r];
        if (ELU) v = v > 0.f ? v : __expf(v) - 1.f;
        if (WF32) Cf[(size_t)grow * N + gcol] = v;
        if (WBF16) Cb[(size_t)grow * N + gcol] = f2b(v);
      }
}

// weights: W1[512,256] -> W1b + W1tb[256,512]; W2[256,64] -> W2b + W2tb[64,256]
__global__ __launch_bounds__(256) void conv_weights(
    const float* __restrict__ W1, const float* __restrict__ W2,
    ushort* __restrict__ W1b, ushort* __restrict__ W1tb,
    ushort* __restrict__ W2b, ushort* __restrict__ W2tb) {
  int i = blockIdx.x * blockDim.x + threadIdx.x;
  if (i < D_IN * D_LAT) {
    ushort b = f2b(W1[i]);
    int r = i / D_LAT, c = i % D_LAT;
    W1b[i] = b;
    W1tb[(size_t)c * D_IN + r] = b;
  }
  if (i < D_LAT * D_EMB) {
    ushort b = f2b(W2[i]);
    int r = i / D_EMB, c = i % D_EMB;
    W2b[i] = b;
    W2tb[(size_t)c * D_LAT + r] = b;
  }
}

// als[i] = h1[i]·a_src, ald[i] = h1[i]·a_dst  (bf16 h1, one wave per node)
__global__ __launch_bounds__(256) void node_logits_b(
    const ushort* __restrict__ h1b, const float* __restrict__ a_src,
    const float* __restrict__ a_dst, float* __restrict__ als,
    float* __restrict__ ald) {
  int wave = threadIdx.x >> 6, lane = threadIdx.x & 63;
  int node = blockIdx.x * 4 + wave;
  if (node >= N_NODES) return;
  ushort4 h = *(const ushort4*)(h1b + (size_t)node * D_LAT + lane * 4);
  float4 as4 = *(const float4*)(a_src + lane * 4);
  float4 ad4 = *(const float4*)(a_dst + lane * 4);
  float hx = b2f(h.x), hy = b2f(h.y), hz = b2f(h.z), hw = b2f(h.w);
  float s = hx * as4.x + hy * as4.y + hz * as4.z + hw * as4.w;
  float d = hx * ad4.x + hy * ad4.y + hz * ad4.z + hw * ad4.w;
  s = wave_reduce_sum(s);
  d = wave_reduce_sum(d);
  if (lane == 0) { als[node] = s; ald[node] = d; }
}

__global__ void hist_kernel(const int* __restrict__ dst,
                            int* __restrict__ counts) {
  int e = blockIdx.x * blockDim.x + threadIdx.x;
  if (e < N_EDGES) atomicAdd(&counts[dst[e]], 1);
}

// --------- hierarchical exclusive scan: counts[N] -> rowptr[N+1] ----------
#define SCAN_NBLK ((N_NODES + 511) / 512)

__global__ __launch_bounds__(512) void scan_phase1(
    const int* __restrict__ counts, int* __restrict__ rowptr,
    int* __restrict__ bsum) {
  __shared__ int wsum[9];
  int idx = blockIdx.x * 512 + threadIdx.x;
  int lane = threadIdx.x & 63, wv = threadIdx.x >> 6;
  int c = (idx < N_NODES) ? counts[idx] : 0;
  int v = c;
#pragma unroll
  for (int off = 1; off < 64; off <<= 1) {
    int t = __shfl_up(v, off, 64);
    if (lane >= off) v += t;
  }
  if (lane == 63) wsum[wv] = v;
  __syncthreads();
  if (threadIdx.x == 0) {
    int r = 0;
    for (int i = 0; i < 8; i++) { int t = wsum[i]; wsum[i] = r; r += t; }
    bsum[blockIdx.x] = r;
  }
  __syncthreads();
  if (idx < N_NODES) rowptr[idx] = wsum[wv] + v - c;  // block-local exclusive
}

__global__ __launch_bounds__(128) void scan_phase2(int* __restrict__ bsum) {
  __shared__ int s[128];
  int tid = threadIdx.x;
  int v = (tid < SCAN_NBLK) ? bsum[tid] : 0;
  s[tid] = v;
  __syncthreads();
  for (int off = 1; off < 128; off <<= 1) {
    int t = (tid >= off) ? s[tid - off] : 0;
    __syncthreads();
    s[tid] += t;
    __syncthreads();
  }
  if (tid < SCAN_NBLK) bsum[tid] = s[tid] - v;  // exclusive
}

__global__ __launch_bounds__(512) void scan_phase3(
    int* __restrict__ rowptr, const int* __restrict__ bsum,
    const int* __restrict__ counts) {
  int idx = blockIdx.x * 512 + threadIdx.x;
  if (idx < N_NODES) {
    int r = rowptr[idx] + bsum[blockIdx.x];
    rowptr[idx] = r;
    if (idx == N_NODES - 1) rowptr[N_NODES] = r + counts[idx];
  }
}

__global__ void scatter_kernel(const int* __restrict__ src,
                               const int* __restrict__ dst,
                               const float* __restrict__ als,
                               const float* __restrict__ ald,
                               const int* __restrict__ rowptr,
                               int* __restrict__ fill, int* __restrict__ ssrc,
                               float* __restrict__ slogit) {
  int e = blockIdx.x * blockDim.x + threadIdx.x;
  if (e >= N_EDGES) return;
  int s = src[e], d = dst[e];
  int pos = rowptr[d] + atomicAdd(&fill[d], 1);
  float x = als[s] + ald[d];
  slogit[pos] = (x > 0.f) ? x : NEG_SLOPE * x;
  ssrc[pos] = s;
}

// segment softmax in place: slogit -> normalized alpha. One wave per node.
__global__ __launch_bounds__(256) void alpha_kernel(
    const int* __restrict__ rowptr, float* __restrict__ slogit) {
  int wave = threadIdx.x >> 6, lane = threadIdx.x & 63;
  int node = blockIdx.x * 4 + wave;
  if (node >= N_NODES) return;
  int beg = rowptr[node], end = rowptr[node + 1];
  float m = -INFINITY;
  for (int e = beg + lane; e < end; e += 64) m = fmaxf(m, slogit[e]);
  m = wave_reduce_max(m);
  float s = 0.f;
  for (int e = beg + lane; e < end; e += 64) s += __expf(slogit[e] - m);
  s = wave_reduce_sum(s);
  float inv = (s > 0.f) ? 1.f / s : 0.f;
  for (int e = beg + lane; e < end; e += 64)
    slogit[e] = __expf(slogit[e] - m) * inv;
}

// weighted gather + ELU over 256-dim bf16 rows. One wave per node;
// half-waves (32 lanes x ushort8 = 512B row) process alternate edges.
__global__ __launch_bounds__(256) void agg_bf16(
    const ushort* __restrict__ feat, const int* __restrict__ rowptr,
    const int* __restrict__ ssrc, const float* __restrict__ alpha,
    ushort* __restrict__ out) {
  int wave = threadIdx.x >> 6, lane = threadIdx.x & 63;
  int node = blockIdx.x * 4 + wave;
  if (node >= N_NODES) return;
  int beg = rowptr[node], end = rowptr[node + 1];
  int half = lane >> 5, hl = lane & 31;
  float acc[8] = {};
  int e = beg + half;
  for (; e + 2 < end; e += 4) {  // 2 edges per half in flight
    float a0 = alpha[e];
    int s0 = ssrc[e];
    float a1 = alpha[e + 2];
    int s1 = ssrc[e + 2];
    u16x8 h0 = *(const u16x8*)(feat + (size_t)s0 * D_LAT + hl * 8);
    u16x8 h1 = *(const u16x8*)(feat + (size_t)s1 * D_LAT + hl * 8);
#pragma unroll
    for (int q = 0; q < 8; q++) acc[q] += a0 * b2f(h0[q]);
#pragma unroll
    for (int q = 0; q < 8; q++) acc[q] += a1 * b2f(h1[q]);
  }
  for (; e < end; e += 2) {
    float a = alpha[e];
    int s = ssrc[e];
    u16x8 h = *(const u16x8*)(feat + (size_t)s * D_LAT + hl * 8);
#pragma unroll
    for (int q = 0; q < 8; q++) acc[q] += a * b2f(h[q]);
  }
#pragma unroll
  for (int q = 0; q < 8; q++) acc[q] += __shfl_xor(acc[q], 32, 64);
  if (half == 0) {
    u16x8 o;
#pragma unroll
    for (int q = 0; q < 8; q++) {
      float v = acc[q];
      o[q] = f2b(v > 0.f ? v : __expf(v) - 1.f);
    }
    *(u16x8*)(out + (size_t)node * D_LAT + hl * 8) = o;
  }
}

// weighted gather over 64-dim bf16 rows (NO elu — applied later in GEMM3).
// One wave per node; quarter-waves (16 lanes x ushort4 = 128B row), 4 edges
// in flight per wave.
__global__ __launch_bounds__(256) void agg_emb(
    const ushort* __restrict__ feat, const int* __restrict__ rowptr,
    const int* __restrict__ ssrc, const float* __restrict__ alpha,
    ushort* __restrict__ out) {
  int wave = threadIdx.x >> 6, lane = threadIdx.x & 63;
  int node = blockIdx.x * 4 + wave;
  if (node >= N_NODES) return;
  int beg = rowptr[node], end = rowptr[node + 1];
  int q = lane >> 4, ql = lane & 15;
  float acc[4] = {};
  for (int e = beg + q; e < end; e += 4) {
    float a = alpha[e];
    int s = ssrc[e];
    ushort4 h = *(const ushort4*)(feat + (size_t)s * D_EMB + ql * 4);
    acc[0] += a * b2f(h.x);
    acc[1] += a * b2f(h.y);
    acc[2] += a * b2f(h.z);
    acc[3] += a * b2f(h.w);
  }
#pragma unroll
  for (int k = 0; k < 4; k++) {
    acc[k] += __shfl_xor(acc[k], 16, 64);
    acc[k] += __shfl_xor(acc[k], 32, 64);
  }
  if (q == 0) {
    ushort4 o;
    o.x = f2b(acc[0]); o.y = f2b(acc[1]); o.z = f2b(acc[2]); o.w = f2b(acc[3]);
    *(ushort4*)(out + (size_t)node * D_EMB + ql * 4) = o;
  }
}

extern "C" void kernel_launch(void* const* d_in, const int* in_sizes, int n_in,
                              void* d_out, int out_size, void* d_ws,
                              size_t ws_size, hipStream_t stream) {
  const float* x = (const float*)d_in[0];
  const float* W1 = (const float*)d_in[1];
  const float* a1s = (const float*)d_in[2];
  const float* a1d = (const float*)d_in[3];
  const float* W2 = (const float*)d_in[4];
  const int* ge = (const int*)d_in[5];
  const int* esrc = ge;
  const int* edst = ge + N_EDGES;

  float* out = (float*)d_out;
  float* emb = out;                              // [N, 64]
  float* recon = out + (size_t)N_NODES * D_EMB;  // [N, 512]

  char* w = (char*)d_ws;
  ushort* h1b = (ushort*)w;    w += (size_t)N_NODES * D_LAT * 2;  // reused as decb
  ushort* interb = (ushort*)w; w += (size_t)N_NODES * D_LAT * 2;  // reused as aggEb
  ushort* embb = (ushort*)w;   w += (size_t)N_NODES * D_EMB * 2;
  ushort* W1b = (ushort*)w;    w += (size_t)D_IN * D_LAT * 2;
  ushort* W1tb = (ushort*)w;   w += (size_t)D_LAT * D_IN * 2;
  ushort* W2b = (ushort*)w;    w += (size_t)D_LAT * D_EMB * 2;
  ushort* W2tb = (ushort*)w;   w += (size_t)D_EMB * D_LAT * 2;
  float* als = (float*)w;      w += (size_t)N_NODES * 4;
  float* ald = (float*)w;      w += (size_t)N_NODES * 4;
  int* counts = (int*)w;       w += (size_t)N_NODES * 4;
  int* rowptr = (int*)w;       w += (size_t)(N_NODES + 4) * 4;
  int* fill = (int*)w;         w += (size_t)N_NODES * 4;
  int* bsum = (int*)w;         w += 128 * 4;
  int* ssrc = (int*)w;         w += (size_t)N_EDGES * 4;
  float* slogit = (float*)w;   w += (size_t)N_EDGES * 4;

  hipMemsetAsync(counts, 0, N_NODES * 4, stream);
  hipMemsetAsync(fill, 0, N_NODES * 4, stream);

  dim3 b256(256), b512(512);
  const int MB = (N_NODES + 127) / 128;  // 391

  // 0. weight conversions (x converted inline in GEMM1)
  conv_weights<<<(D_IN * D_LAT + 255) / 256, b256, 0, stream>>>(
      W1, W2, W1b, W1tb, W2b, W2tb);

  // 1. h1 = x @ W1 (A f32 staged inline; BN=256 -> x read exactly once)
  gemm_mfma<128, 256, 2, 4, 1, 0, 1, 0><<<dim3(1, MB), b512, 0, stream>>>(
      x, W1tb, (float*)nullptr, h1b, N_NODES, D_LAT, D_IN);
  // 2. per-node attention logits from bf16 h1
  node_logits_b<<<(N_NODES + 3) / 4, b256, 0, stream>>>(h1b, a1s, a1d, als, ald);
  // 3-5. CSR by dst (hist + hierarchical scan + scatter)
  hist_kernel<<<(N_EDGES + 255) / 256, b256, 0, stream>>>(edst, counts);
  scan_phase1<<<SCAN_NBLK, 512, 0, stream>>>(counts, rowptr, bsum);
  scan_phase2<<<1, 128, 0, stream>>>(bsum);
  scan_phase3<<<SCAN_NBLK, 512, 0, stream>>>(rowptr, bsum, counts);
  scatter_kernel<<<(N_EDGES + 255) / 256, b256, 0, stream>>>(
      esrc, edst, als, ald, rowptr, fill, ssrc, slogit);
  // 6. normalized alpha in place (tied attention -> shared by both aggs)
  alpha_kernel<<<(N_NODES + 3) / 4, b256, 0, stream>>>(rowptr, slogit);
  // 7. inter = elu(sum alpha * h1[src])
  agg_bf16<<<(N_NODES + 3) / 4, b256, 0, stream>>>(h1b, rowptr, ssrc, slogit,
                                                   interb);
  // 8. emb = inter @ W2 (f32 to d_out + bf16 copy)
  gemm_mfma<128, 64, 2, 2, 0, 1, 1, 0><<<dim3(1, MB), b256, 0, stream>>>(
      interb, W2tb, emb, embb, N_NODES, D_EMB, D_LAT);
  // 9. aggE = sum alpha * emb[src]  (linearity: agg(emb @ W2^T) =
  //    agg(emb) @ W2^T -- h3 never materialized). interb is free now.
  ushort* aggEb = interb;
  agg_emb<<<(N_NODES + 3) / 4, b256, 0, stream>>>(embb, rowptr, ssrc, slogit,
                                                  aggEb);
  // 10. dec = elu(aggE @ W2^T)  (ELU fused in epilogue) -> reuse h1b
  ushort* decb = h1b;
  gemm_mfma<128, 256, 2, 4, 0, 0, 1, 1><<<dim3(1, MB), b512, 0, stream>>>(
      aggEb, W2b, (float*)nullptr, decb, N_NODES, D_LAT, D_EMB);
  // 11. recon = dec @ W1^T (f32 to d_out; BN=256 halves decb re-reads)
  gemm_mfma<128, 256, 2, 4, 0, 1, 0, 0><<<dim3(D_IN / 256, MB), b512, 0, stream>>>(
      decb, W1b, recon, (ushort*)nullptr, N_NODES, D_IN, D_LAT);
}

// Round 7
// 291.140 us; speedup vs baseline: 3.7944x; 1.0390x over previous
//
#include <hip/hip_runtime.h>
#include <math.h>

#define N_NODES 50000
#define N_EDGES 800000
#define D_IN 512
#define D_LAT 256
#define D_EMB 64
#define NEG_SLOPE 0.2f

typedef __attribute__((ext_vector_type(8))) short bf16x8;
typedef __attribute__((ext_vector_type(8))) unsigned short u16x8;
typedef __attribute__((ext_vector_type(4))) float f32x4;

__device__ __forceinline__ ushort f2b(float f) {
  union { float f; unsigned u; } v; v.f = f;
  return (ushort)((v.u + 0x7fffu + ((v.u >> 16) & 1u)) >> 16);
}
__device__ __forceinline__ float b2f(ushort h) {
  union { unsigned u; float f; } v; v.u = ((unsigned)h) << 16;
  return v.f;
}

__device__ __forceinline__ float wave_reduce_sum(float v) {
#pragma unroll
  for (int off = 32; off > 0; off >>= 1) v += __shfl_xor(v, off, 64);
  return v;
}
__device__ __forceinline__ float wave_reduce_max(float v) {
#pragma unroll
  for (int off = 32; off > 0; off >>= 1) v = fmaxf(v, __shfl_xor(v, off, 64));
  return v;
}

// ---------------------------------------------------------------------------
// bf16 MFMA GEMM: C[M,N] = A[M,K] @ B[N,K]^T  (row-major).
// AF32=1: A f32, staged regs+cvt+ds_write (linear LDS layout).
// AF32=0: A bf16 via global_load_lds w16.  ELU: fused elu epilogue.
// LOGIT=1 (requires grid.x==1, BN==N): also emit als/ald = C·a_src / C·a_dst
// from the f32 accumulators via 16-lane shfl + LDS f32 atomics.
// LDS tiles [rows][32] (64B rows): fragment reads tile 1KB.
// ---------------------------------------------------------------------------
template <int BM, int BN, int WR, int WC, int AF32, int WF32, int WBF16,
          int ELU, int LOGIT>
__global__ __launch_bounds__(WR * WC * 64) void gemm_mfma(
    const void* __restrict__ Aptr, const ushort* __restrict__ B,
    float* __restrict__ Cf, ushort* __restrict__ Cb, int M, int N, int K,
    const float* __restrict__ a_src, const float* __restrict__ a_dst,
    float* __restrict__ als, float* __restrict__ ald) {
  constexpr int BK = 32;
  constexpr int WTM = BM / WR, WTN = BN / WC;
  constexpr int FM = WTM / 16, FN = WTN / 16;
  constexpr int NT = WR * WC * 64;
  constexpr int AIT = (BM * BK * 2) / (NT * 16);
  constexpr int BIT_ = (BN * BK * 2) / (NT * 16);
  __shared__ ushort As[BM][BK];
  __shared__ ushort Bs[BN][BK];
  const int tid = threadIdx.x, lane = tid & 63, wid = tid >> 6;
  const int wr = wid / WC, wc = wid % WC;
  const int bm = blockIdx.y * BM, bn = blockIdx.x * BN;
  f32x4 acc[FM][FN] = {};

  for (int k0 = 0; k0 < K; k0 += BK) {
    if constexpr (AF32) {
      const float* Af = (const float*)Aptr;
#pragma unroll
      for (int it = 0; it < AIT; ++it) {
        int off = it * (NT * 16) + tid * 16;  // byte offset in bf16 tile
        int row = off >> 6;                   // 64 B per LDS row
        int ecol = (off & 63) >> 1;           // element col (x8)
        int grow = bm + row; grow = grow < M ? grow : (M - 1);
        const float* g = Af + (size_t)grow * K + k0 + ecol;
        float4 f0 = *(const float4*)g;
        float4 f1 = *(const float4*)(g + 4);
        u16x8 hb;
        hb[0] = f2b(f0.x); hb[1] = f2b(f0.y); hb[2] = f2b(f0.z); hb[3] = f2b(f0.w);
        hb[4] = f2b(f1.x); hb[5] = f2b(f1.y); hb[6] = f2b(f1.z); hb[7] = f2b(f1.w);
        *(u16x8*)((char*)&As[0][0] + off) = hb;
      }
    } else {
      const ushort* Ab = (const ushort*)Aptr;
#pragma unroll
      for (int it = 0; it < AIT; ++it) {
        int off = it * (NT * 16) + tid * 16;
        int row = off >> 6;
        int grow = bm + row; grow = grow < M ? grow : (M - 1);
        const ushort* g = Ab + (size_t)grow * K + k0 + ((off & 63) >> 1);
        __builtin_amdgcn_global_load_lds(
            (const __attribute__((address_space(1))) void*)g,
            (__attribute__((address_space(3))) void*)((char*)&As[0][0] + off),
            16, 0, 0);
      }
    }
#pragma unroll
    for (int it = 0; it < BIT_; ++it) {
      int off = it * (NT * 16) + tid * 16;
      int row = off >> 6;
      const ushort* g = B + (size_t)(bn + row) * K + k0 + ((off & 63) >> 1);
      __builtin_amdgcn_global_load_lds(
          (const __attribute__((address_space(1))) void*)g,
          (__attribute__((address_space(3))) void*)((char*)&Bs[0][0] + off),
          16, 0, 0);
    }
    __syncthreads();
    const int kb = (lane >> 4) * 8, rl = lane & 15;
    bf16x8 af[FM], bfr[FN];
#pragma unroll
    for (int i = 0; i < FM; ++i)
      af[i] = *(const bf16x8*)&As[wr * WTM + i * 16 + rl][kb];
#pragma unroll
    for (int j = 0; j < FN; ++j)
      bfr[j] = *(const bf16x8*)&Bs[wc * WTN + j * 16 + rl][kb];
#pragma unroll
    for (int i = 0; i < FM; ++i)
#pragma unroll
      for (int j = 0; j < FN; ++j)
        acc[i][j] = __builtin_amdgcn_mfma_f32_16x16x32_bf16(af[i], bfr[j],
                                                            acc[i][j], 0, 0, 0);
    __syncthreads();
  }
  // epilogue: C/D layout col=lane&15, row=(lane>>4)*4+reg (m89-verified)
  const int cl = lane & 15, rg = (lane >> 4) * 4;
#pragma unroll
  for (int i = 0; i < FM; ++i)
#pragma unroll
    for (int j = 0; j < FN; ++j)
#pragma unroll
      for (int r = 0; r < 4; ++r) {
        int grow = bm + wr * WTM + i * 16 + rg + r;
        if (grow >= M) continue;
        int gcol = bn + wc * WTN + j * 16 + cl;
        float v = acc[i][j][r];
        if (ELU) v = v > 0.f ? v : __expf(v) - 1.f;
        if (WF32) Cf[(size_t)grow * N + gcol] = v;
        if (WBF16) Cb[(size_t)grow * N + gcol] = f2b(v);
      }
  if constexpr (LOGIT) {
    __shared__ float alsP[BM], aldP[BM];
    for (int t = tid; t < BM; t += NT) { alsP[t] = 0.f; aldP[t] = 0.f; }
    __syncthreads();
    float asv[FN], adv[FN];
#pragma unroll
    for (int j = 0; j < FN; ++j) {
      int col = bn + wc * WTN + j * 16 + cl;
      asv[j] = a_src[col];
      adv[j] = a_dst[col];
    }
#pragma unroll
    for (int i = 0; i < FM; ++i)
#pragma unroll
      for (int r = 0; r < 4; ++r) {
        float s = 0.f, d = 0.f;
#pragma unroll
        for (int j = 0; j < FN; ++j) {
          s += acc[i][j][r] * asv[j];
          d += acc[i][j][r] * adv[j];
        }
#pragma unroll
        for (int off = 1; off < 16; off <<= 1) {
          s += __shfl_xor(s, off, 64);
          d += __shfl_xor(d, off, 64);
        }
        if (cl == 0) {
          int row = wr * WTM + i * 16 + rg + r;
          atomicAdd(&alsP[row], s);
          atomicAdd(&aldP[row], d);
        }
      }
    __syncthreads();
    for (int t = tid; t < BM; t += NT) {
      int gr = bm + t;
      if (gr < M) { als[gr] = alsP[t]; ald[gr] = aldP[t]; }
    }
  }
}

// weights conv (i < 512*256) + edge histogram (i < N_EDGES), one pass
__global__ __launch_bounds__(256) void conv_weights_hist(
    const float* __restrict__ W1, const float* __restrict__ W2,
    ushort* __restrict__ W1b, ushort* __restrict__ W1tb,
    ushort* __restrict__ W2b, ushort* __restrict__ W2tb,
    const int* __restrict__ dst, int* __restrict__ counts) {
  int i = blockIdx.x * blockDim.x + threadIdx.x;
  if (i < D_IN * D_LAT) {
    ushort b = f2b(W1[i]);
    int r = i / D_LAT, c = i % D_LAT;
    W1b[i] = b;
    W1tb[(size_t)c * D_IN + r] = b;
  }
  if (i < D_LAT * D_EMB) {
    ushort b = f2b(W2[i]);
    int r = i / D_EMB, c = i % D_EMB;
    W2b[i] = b;
    W2tb[(size_t)c * D_LAT + r] = b;
  }
  if (i < N_EDGES) atomicAdd(&counts[dst[i]], 1);
}

// --------- hierarchical exclusive scan (2-phase; consumers add bsum) -------
#define SCAN_NBLK ((N_NODES + 511) / 512)

__global__ __launch_bounds__(512) void scan_phase1(
    const int* __restrict__ counts, int* __restrict__ rowptr,
    int* __restrict__ bsum) {
  __shared__ int wsum[9];
  int idx = blockIdx.x * 512 + threadIdx.x;
  int lane = threadIdx.x & 63, wv = threadIdx.x >> 6;
  int c = (idx < N_NODES) ? counts[idx] : 0;
  int v = c;
#pragma unroll
  for (int off = 1; off < 64; off <<= 1) {
    int t = __shfl_up(v, off, 64);
    if (lane >= off) v += t;
  }
  if (lane == 63) wsum[wv] = v;
  __syncthreads();
  if (threadIdx.x == 0) {
    int r = 0;
    for (int i = 0; i < 8; i++) { int t = wsum[i]; wsum[i] = r; r += t; }
    bsum[blockIdx.x] = r;
  }
  __syncthreads();
  if (idx < N_NODES) rowptr[idx] = wsum[wv] + v - c;  // block-local exclusive
}

__global__ __launch_bounds__(128) void scan_phase2(int* __restrict__ bsum) {
  __shared__ int s[128];
  int tid = threadIdx.x;
  int v = (tid < SCAN_NBLK) ? bsum[tid] : 0;
  s[tid] = v;
  __syncthreads();
  for (int off = 1; off < 128; off <<= 1) {
    int t = (tid >= off) ? s[tid - off] : 0;
    __syncthreads();
    s[tid] += t;
    __syncthreads();
  }
  if (tid < SCAN_NBLK) bsum[tid] = s[tid] - v;  // exclusive
}

__device__ __forceinline__ int grp(const int* rowptr, const int* bsum,
                                   int idx) {
  return rowptr[idx] + bsum[idx >> 9];
}
__device__ __forceinline__ int grp_end(const int* rowptr, const int* bsum,
                                       int node) {
  return (node + 1 < N_NODES) ? rowptr[node + 1] + bsum[(node + 1) >> 9]
                              : N_EDGES;
}

__global__ void scatter_kernel(const int* __restrict__ src,
                               const int* __restrict__ dst,
                               const float* __restrict__ als,
                               const float* __restrict__ ald,
                               const int* __restrict__ rowptr,
                               const int* __restrict__ bsum,
                               int* __restrict__ fill, int* __restrict__ ssrc,
                               float* __restrict__ slogit) {
  int e = blockIdx.x * blockDim.x + threadIdx.x;
  if (e >= N_EDGES) return;
  int s = src[e], d = dst[e];
  int pos = grp(rowptr, bsum, d) + atomicAdd(&fill[d], 1);
  float x = als[s] + ald[d];
  slogit[pos] = (x > 0.f) ? x : NEG_SLOPE * x;
  ssrc[pos] = s;
}

// agg1 + fused softmax: raw slogit in, normalized alpha out (for agg_emb),
// inter = elu(sum alpha*h1[src]) out. One wave per node; half-waves (32
// lanes x ushort8 = 512B row) process alternate edges.
__global__ __launch_bounds__(256) void agg_bf16_sm(
    const ushort* __restrict__ feat, const int* __restrict__ rowptr,
    const int* __restrict__ bsum, const int* __restrict__ ssrc,
    const float* __restrict__ slogit, float* __restrict__ alphaOut,
    ushort* __restrict__ out) {
  int wave = threadIdx.x >> 6, lane = threadIdx.x & 63;
  int node = blockIdx.x * 4 + wave;
  if (node >= N_NODES) return;
  int beg = grp(rowptr, bsum, node), end = grp_end(rowptr, bsum, node);
  // wave-strided max & sum of exp (raw logits, never overwritten)
  float m = -INFINITY;
  for (int e = beg + lane; e < end; e += 64) m = fmaxf(m, slogit[e]);
  m = wave_reduce_max(m);
  float s = 0.f;
  for (int e = beg + lane; e < end; e += 64) s += __expf(slogit[e] - m);
  s = wave_reduce_sum(s);
  float inv = (s > 0.f) ? 1.f / s : 0.f;
  // gather: half-wave per edge, alpha recomputed in-register + written once
  int half = lane >> 5, hl = lane & 31;
  float acc[8] = {};
  int e = beg + half;
  for (; e + 2 < end; e += 4) {
    float a0 = __expf(slogit[e] - m) * inv;
    int s0 = ssrc[e];
    float a1 = __expf(slogit[e + 2] - m) * inv;
    int s1 = ssrc[e + 2];
    if (hl == 0) { alphaOut[e] = a0; alphaOut[e + 2] = a1; }
    u16x8 h0 = *(const u16x8*)(feat + (size_t)s0 * D_LAT + hl * 8);
    u16x8 h1 = *(const u16x8*)(feat + (size_t)s1 * D_LAT + hl * 8);
#pragma unroll
    for (int q = 0; q < 8; q++) acc[q] += a0 * b2f(h0[q]);
#pragma unroll
    for (int q = 0; q < 8; q++) acc[q] += a1 * b2f(h1[q]);
  }
  for (; e < end; e += 2) {
    float a = __expf(slogit[e] - m) * inv;
    int s2 = ssrc[e];
    if (hl == 0) alphaOut[e] = a;
    u16x8 h = *(const u16x8*)(feat + (size_t)s2 * D_LAT + hl * 8);
#pragma unroll
    for (int q = 0; q < 8; q++) acc[q] += a * b2f(h[q]);
  }
#pragma unroll
  for (int q = 0; q < 8; q++) acc[q] += __shfl_xor(acc[q], 32, 64);
  if (half == 0) {
    u16x8 o;
#pragma unroll
    for (int q = 0; q < 8; q++) {
      float v = acc[q];
      o[q] = f2b(v > 0.f ? v : __expf(v) - 1.f);
    }
    *(u16x8*)(out + (size_t)node * D_LAT + hl * 8) = o;
  }
}

// weighted gather over 64-dim bf16 rows (no elu — fused into next GEMM).
// One wave per node; quarter-waves (16 lanes x ushort4 = 128B row).
__global__ __launch_bounds__(256) void agg_emb(
    const ushort* __restrict__ feat, const int* __restrict__ rowptr,
    const int* __restrict__ bsum, const int* __restrict__ ssrc,
    const float* __restrict__ alpha, ushort* __restrict__ out) {
  int wave = threadIdx.x >> 6, lane = threadIdx.x & 63;
  int node = blockIdx.x * 4 + wave;
  if (node >= N_NODES) return;
  int beg = grp(rowptr, bsum, node), end = grp_end(rowptr, bsum, node);
  int q = lane >> 4, ql = lane & 15;
  float acc[4] = {};
  for (int e = beg + q; e < end; e += 4) {
    float a = alpha[e];
    int s = ssrc[e];
    ushort4 h = *(const ushort4*)(feat + (size_t)s * D_EMB + ql * 4);
    acc[0] += a * b2f(h.x);
    acc[1] += a * b2f(h.y);
    acc[2] += a * b2f(h.z);
    acc[3] += a * b2f(h.w);
  }
#pragma unroll
  for (int k = 0; k < 4; k++) {
    acc[k] += __shfl_xor(acc[k], 16, 64);
    acc[k] += __shfl_xor(acc[k], 32, 64);
  }
  if (q == 0) {
    ushort4 o;
    o.x = f2b(acc[0]); o.y = f2b(acc[1]); o.z = f2b(acc[2]); o.w = f2b(acc[3]);
    *(ushort4*)(out + (size_t)node * D_EMB + ql * 4) = o;
  }
}

extern "C" void kernel_launch(void* const* d_in, const int* in_sizes, int n_in,
                              void* d_out, int out_size, void* d_ws,
                              size_t ws_size, hipStream_t stream) {
  const float* x = (const float*)d_in[0];
  const float* W1 = (const float*)d_in[1];
  const float* a1s = (const float*)d_in[2];
  const float* a1d = (const float*)d_in[3];
  const float* W2 = (const float*)d_in[4];
  const int* ge = (const int*)d_in[5];
  const int* esrc = ge;
  const int* edst = ge + N_EDGES;

  float* out = (float*)d_out;
  float* emb = out;                              // [N, 64]
  float* recon = out + (size_t)N_NODES * D_EMB;  // [N, 512]

  char* w = (char*)d_ws;
  ushort* h1b = (ushort*)w;    w += (size_t)N_NODES * D_LAT * 2;  // reused as decb
  ushort* interb = (ushort*)w; w += (size_t)N_NODES * D_LAT * 2;  // reused as aggEb
  ushort* embb = (ushort*)w;   w += (size_t)N_NODES * D_EMB * 2;
  ushort* W1b = (ushort*)w;    w += (size_t)D_IN * D_LAT * 2;
  ushort* W1tb = (ushort*)w;   w += (size_t)D_LAT * D_IN * 2;
  ushort* W2b = (ushort*)w;    w += (size_t)D_LAT * D_EMB * 2;
  ushort* W2tb = (ushort*)w;   w += (size_t)D_EMB * D_LAT * 2;
  float* als = (float*)w;      w += (size_t)N_NODES * 4;
  float* ald = (float*)w;      w += (size_t)N_NODES * 4;
  int* counts = (int*)w;       w += (size_t)N_NODES * 4;  // adjacent to fill:
  int* fill = (int*)w;         w += (size_t)N_NODES * 4;  // one memset covers both
  int* rowptr = (int*)w;       w += (size_t)(N_NODES + 4) * 4;
  int* bsum = (int*)w;         w += 128 * 4;
  int* ssrc = (int*)w;         w += (size_t)N_EDGES * 4;
  float* slogit = (float*)w;   w += (size_t)N_EDGES * 4;
  float* alphaO = (float*)w;   w += (size_t)N_EDGES * 4;

  hipMemsetAsync(counts, 0, (size_t)N_NODES * 8, stream);  // counts + fill

  dim3 b256(256), b512(512);
  const int MB = (N_NODES + 127) / 128;  // 391

  // 0. weight conversions + edge histogram (one pass)
  conv_weights_hist<<<(N_EDGES + 255) / 256, b256, 0, stream>>>(
      W1, W2, W1b, W1tb, W2b, W2tb, edst, counts);

  // 1. h1 = x @ W1 (A f32 staged inline; BN=256 -> x read once) + fused
  //    logits als/ald from f32 accumulators
  gemm_mfma<128, 256, 2, 4, 1, 0, 1, 0, 1><<<dim3(1, MB), b512, 0, stream>>>(
      x, W1tb, (float*)nullptr, h1b, N_NODES, D_LAT, D_IN, a1s, a1d, als, ald);
  // 2-3. CSR by dst (2-phase scan; consumers add bsum inline)
  scan_phase1<<<SCAN_NBLK, 512, 0, stream>>>(counts, rowptr, bsum);
  scan_phase2<<<1, 128, 0, stream>>>(bsum);
  scatter_kernel<<<(N_EDGES + 255) / 256, b256, 0, stream>>>(
      esrc, edst, als, ald, rowptr, bsum, fill, ssrc, slogit);
  // 4. inter = elu(sum alpha*h1[src]); softmax fused; alpha written for agg3
  agg_bf16_sm<<<(N_NODES + 3) / 4, b256, 0, stream>>>(
      h1b, rowptr, bsum, ssrc, slogit, alphaO, interb);
  // 5. emb = inter @ W2 (f32 to d_out + bf16 copy)
  gemm_mfma<128, 64, 2, 2, 0, 1, 1, 0, 0><<<dim3(1, MB), b256, 0, stream>>>(
      interb, W2tb, emb, embb, N_NODES, D_EMB, D_LAT, nullptr, nullptr,
      nullptr, nullptr);
  // 6. aggE = sum alpha * emb[src]  (linearity: agg(emb@W2^T)=agg(emb)@W2^T)
  ushort* aggEb = interb;
  agg_emb<<<(N_NODES + 3) / 4, b256, 0, stream>>>(embb, rowptr, bsum, ssrc,
                                                  alphaO, aggEb);
  // 7. dec = elu(aggE @ W2^T) (ELU fused) -> reuse h1b
  ushort* decb = h1b;
  gemm_mfma<128, 256, 2, 4, 0, 0, 1, 1, 0><<<dim3(1, MB), b512, 0, stream>>>(
      aggEb, W2b, (float*)nullptr, decb, N_NODES, D_LAT, D_EMB, nullptr,
      nullptr, nullptr, nullptr);
  // 8. recon = dec @ W1^T (f32 to d_out)
  gemm_mfma<128, 256, 2, 4, 0, 1, 0, 0, 0><<<dim3(D_IN / 256, MB), b512, 0,
                                              stream>>>(
      decb, W1b, recon, (ushort*)nullptr, N_NODES, D_IN, D_LAT, nullptr,
      nullptr, nullptr, nullptr);
}

// Round 8
// 279.665 us; speedup vs baseline: 3.9501x; 1.0410x over previous
//
#include <hip/hip_runtime.h>
#include <math.h>

#define N_NODES 50000
#define N_EDGES 800000
#define D_IN 512
#define D_LAT 256
#define D_EMB 64
#define NEG_SLOPE 0.2f

typedef __attribute__((ext_vector_type(8))) short bf16x8;
typedef __attribute__((ext_vector_type(8))) unsigned short u16x8;
typedef __attribute__((ext_vector_type(4))) float f32x4;

__device__ __forceinline__ ushort f2b(float f) {
  union { float f; unsigned u; } v; v.f = f;
  return (ushort)((v.u + 0x7fffu + ((v.u >> 16) & 1u)) >> 16);
}
__device__ __forceinline__ float b2f(ushort h) {
  union { unsigned u; float f; } v; v.u = ((unsigned)h) << 16;
  return v.f;
}

__device__ __forceinline__ float wave_reduce_sum(float v) {
#pragma unroll
  for (int off = 32; off > 0; off >>= 1) v += __shfl_xor(v, off, 64);
  return v;
}

// ---------------------------------------------------------------------------
// bf16 MFMA GEMM: C[M,N] = A[M,K] @ B[N,K]^T  (row-major).
// AF32=1: A f32, staged regs+cvt+ds_write (linear LDS layout).
// AF32=0: A bf16 via global_load_lds w16.  ELU: fused elu epilogue.
// LOGIT=1 (requires grid.x==1, BN==N): also emit als/ald = C·a_src / C·a_dst
// from the f32 accumulators via 16-lane shfl + LDS f32 atomics.
// LDS tiles [rows][32] (64B rows): fragment reads tile 1KB.
// ---------------------------------------------------------------------------
template <int BM, int BN, int WR, int WC, int AF32, int WF32, int WBF16,
          int ELU, int LOGIT>
__global__ __launch_bounds__(WR * WC * 64) void gemm_mfma(
    const void* __restrict__ Aptr, const ushort* __restrict__ B,
    float* __restrict__ Cf, ushort* __restrict__ Cb, int M, int N, int K,
    const float* __restrict__ a_src, const float* __restrict__ a_dst,
    float* __restrict__ als, float* __restrict__ ald) {
  constexpr int BK = 32;
  constexpr int WTM = BM / WR, WTN = BN / WC;
  constexpr int FM = WTM / 16, FN = WTN / 16;
  constexpr int NT = WR * WC * 64;
  constexpr int AIT = (BM * BK * 2) / (NT * 16);
  constexpr int BIT_ = (BN * BK * 2) / (NT * 16);
  __shared__ ushort As[BM][BK];
  __shared__ ushort Bs[BN][BK];
  const int tid = threadIdx.x, lane = tid & 63, wid = tid >> 6;
  const int wr = wid / WC, wc = wid % WC;
  const int bm = blockIdx.y * BM, bn = blockIdx.x * BN;
  f32x4 acc[FM][FN] = {};

  for (int k0 = 0; k0 < K; k0 += BK) {
    if constexpr (AF32) {
      const float* Af = (const float*)Aptr;
#pragma unroll
      for (int it = 0; it < AIT; ++it) {
        int off = it * (NT * 16) + tid * 16;  // byte offset in bf16 tile
        int row = off >> 6;                   // 64 B per LDS row
        int ecol = (off & 63) >> 1;           // element col (x8)
        int grow = bm + row; grow = grow < M ? grow : (M - 1);
        const float* g = Af + (size_t)grow * K + k0 + ecol;
        float4 f0 = *(const float4*)g;
        float4 f1 = *(const float4*)(g + 4);
        u16x8 hb;
        hb[0] = f2b(f0.x); hb[1] = f2b(f0.y); hb[2] = f2b(f0.z); hb[3] = f2b(f0.w);
        hb[4] = f2b(f1.x); hb[5] = f2b(f1.y); hb[6] = f2b(f1.z); hb[7] = f2b(f1.w);
        *(u16x8*)((char*)&As[0][0] + off) = hb;
      }
    } else {
      const ushort* Ab = (const ushort*)Aptr;
#pragma unroll
      for (int it = 0; it < AIT; ++it) {
        int off = it * (NT * 16) + tid * 16;
        int row = off >> 6;
        int grow = bm + row; grow = grow < M ? grow : (M - 1);
        const ushort* g = Ab + (size_t)grow * K + k0 + ((off & 63) >> 1);
        __builtin_amdgcn_global_load_lds(
            (const __attribute__((address_space(1))) void*)g,
            (__attribute__((address_space(3))) void*)((char*)&As[0][0] + off),
            16, 0, 0);
      }
    }
#pragma unroll
    for (int it = 0; it < BIT_; ++it) {
      int off = it * (NT * 16) + tid * 16;
      int row = off >> 6;
      const ushort* g = B + (size_t)(bn + row) * K + k0 + ((off & 63) >> 1);
      __builtin_amdgcn_global_load_lds(
          (const __attribute__((address_space(1))) void*)g,
          (__attribute__((address_space(3))) void*)((char*)&Bs[0][0] + off),
          16, 0, 0);
    }
    __syncthreads();
    const int kb = (lane >> 4) * 8, rl = lane & 15;
    bf16x8 af[FM], bfr[FN];
#pragma unroll
    for (int i = 0; i < FM; ++i)
      af[i] = *(const bf16x8*)&As[wr * WTM + i * 16 + rl][kb];
#pragma unroll
    for (int j = 0; j < FN; ++j)
      bfr[j] = *(const bf16x8*)&Bs[wc * WTN + j * 16 + rl][kb];
#pragma unroll
    for (int i = 0; i < FM; ++i)
#pragma unroll
      for (int j = 0; j < FN; ++j)
        acc[i][j] = __builtin_amdgcn_mfma_f32_16x16x32_bf16(af[i], bfr[j],
                                                            acc[i][j], 0, 0, 0);
    __syncthreads();
  }
  // epilogue: C/D layout col=lane&15, row=(lane>>4)*4+reg (m89-verified)
  const int cl = lane & 15, rg = (lane >> 4) * 4;
#pragma unroll
  for (int i = 0; i < FM; ++i)
#pragma unroll
    for (int j = 0; j < FN; ++j)
#pragma unroll
      for (int r = 0; r < 4; ++r) {
        int grow = bm + wr * WTM + i * 16 + rg + r;
        if (grow >= M) continue;
        int gcol = bn + wc * WTN + j * 16 + cl;
        float v = acc[i][j][r];
        if (ELU) v = v > 0.f ? v : __expf(v) - 1.f;
        if (WF32) Cf[(size_t)grow * N + gcol] = v;
        if (WBF16) Cb[(size_t)grow * N + gcol] = f2b(v);
      }
  if constexpr (LOGIT) {
    __shared__ float alsP[BM], aldP[BM];
    for (int t = tid; t < BM; t += NT) { alsP[t] = 0.f; aldP[t] = 0.f; }
    __syncthreads();
    float asv[FN], adv[FN];
#pragma unroll
    for (int j = 0; j < FN; ++j) {
      int col = bn + wc * WTN + j * 16 + cl;
      asv[j] = a_src[col];
      adv[j] = a_dst[col];
    }
#pragma unroll
    for (int i = 0; i < FM; ++i)
#pragma unroll
      for (int r = 0; r < 4; ++r) {
        float s = 0.f, d = 0.f;
#pragma unroll
        for (int j = 0; j < FN; ++j) {
          s += acc[i][j][r] * asv[j];
          d += acc[i][j][r] * adv[j];
        }
#pragma unroll
        for (int off = 1; off < 16; off <<= 1) {
          s += __shfl_xor(s, off, 64);
          d += __shfl_xor(d, off, 64);
        }
        if (cl == 0) {
          int row = wr * WTM + i * 16 + rg + r;
          atomicAdd(&alsP[row], s);
          atomicAdd(&aldP[row], d);
        }
      }
    __syncthreads();
    for (int t = tid; t < BM; t += NT) {
      int gr = bm + t;
      if (gr < M) { als[gr] = alsP[t]; ald[gr] = aldP[t]; }
    }
  }
}

// weights conv (i < 512*256) + edge histogram (i < N_EDGES), one pass
__global__ __launch_bounds__(256) void conv_weights_hist(
    const float* __restrict__ W1, const float* __restrict__ W2,
    ushort* __restrict__ W1b, ushort* __restrict__ W1tb,
    ushort* __restrict__ W2b, ushort* __restrict__ W2tb,
    const int* __restrict__ dst, int* __restrict__ counts) {
  int i = blockIdx.x * blockDim.x + threadIdx.x;
  if (i < D_IN * D_LAT) {
    ushort b = f2b(W1[i]);
    int r = i / D_LAT, c = i % D_LAT;
    W1b[i] = b;
    W1tb[(size_t)c * D_IN + r] = b;
  }
  if (i < D_LAT * D_EMB) {
    ushort b = f2b(W2[i]);
    int r = i / D_EMB, c = i % D_EMB;
    W2b[i] = b;
    W2tb[(size_t)c * D_LAT + r] = b;
  }
  if (i < N_EDGES) atomicAdd(&counts[dst[i]], 1);
}

// --------- hierarchical exclusive scan (2-phase; consumers add bsum) -------
#define SCAN_NBLK ((N_NODES + 511) / 512)

__global__ __launch_bounds__(512) void scan_phase1(
    const int* __restrict__ counts, int* __restrict__ rowptr,
    int* __restrict__ bsum) {
  __shared__ int wsum[9];
  int idx = blockIdx.x * 512 + threadIdx.x;
  int lane = threadIdx.x & 63, wv = threadIdx.x >> 6;
  int c = (idx < N_NODES) ? counts[idx] : 0;
  int v = c;
#pragma unroll
  for (int off = 1; off < 64; off <<= 1) {
    int t = __shfl_up(v, off, 64);
    if (lane >= off) v += t;
  }
  if (lane == 63) wsum[wv] = v;
  __syncthreads();
  if (threadIdx.x == 0) {
    int r = 0;
    for (int i = 0; i < 8; i++) { int t = wsum[i]; wsum[i] = r; r += t; }
    bsum[blockIdx.x] = r;
  }
  __syncthreads();
  if (idx < N_NODES) rowptr[idx] = wsum[wv] + v - c;  // block-local exclusive
}

__global__ __launch_bounds__(128) void scan_phase2(int* __restrict__ bsum) {
  __shared__ int s[128];
  int tid = threadIdx.x;
  int v = (tid < SCAN_NBLK) ? bsum[tid] : 0;
  s[tid] = v;
  __syncthreads();
  for (int off = 1; off < 128; off <<= 1) {
    int t = (tid >= off) ? s[tid - off] : 0;
    __syncthreads();
    s[tid] += t;
    __syncthreads();
  }
  if (tid < SCAN_NBLK) bsum[tid] = s[tid] - v;  // exclusive
}

__device__ __forceinline__ int grp(const int* rowptr, const int* bsum,
                                   int idx) {
  return rowptr[idx] + bsum[idx >> 9];
}
__device__ __forceinline__ int grp_end(const int* rowptr, const int* bsum,
                                       int node) {
  return (node + 1 < N_NODES) ? rowptr[node + 1] + bsum[(node + 1) >> 9]
                              : N_EDGES;
}

__global__ void scatter_kernel(const int* __restrict__ src,
                               const int* __restrict__ dst,
                               const float* __restrict__ als,
                               const float* __restrict__ ald,
                               const int* __restrict__ rowptr,
                               const int* __restrict__ bsum,
                               int* __restrict__ fill, int* __restrict__ ssrc,
                               float* __restrict__ slogit) {
  int e = blockIdx.x * blockDim.x + threadIdx.x;
  if (e >= N_EDGES) return;
  int s = src[e], d = dst[e];
  int pos = grp(rowptr, bsum, d) + atomicAdd(&fill[d], 1);
  float x = als[s] + ald[d];
  slogit[pos] = (x > 0.f) ? x : NEG_SLOPE * x;
  ssrc[pos] = s;
}

// agg1 + fused softmax (fixed-shift: no max pass; logits bounded ~|8| so
// exp() is safe in f32 and ratios are shift-invariant).
// pass1: sum of e=exp(slogit) wave-strided; e written to alphaE (coalesced),
//        inv written per node (for agg_emb).
// pass2: half-wave per edge, 4 edges unrolled (8 row-loads in flight/wave);
//        exp recomputed in-register (1 v_exp per 2 edges); normalize at end.
__global__ __launch_bounds__(256) void agg_bf16_sm(
    const ushort* __restrict__ feat, const int* __restrict__ rowptr,
    const int* __restrict__ bsum, const int* __restrict__ ssrc,
    const float* __restrict__ slogit, float* __restrict__ alphaE,
    float* __restrict__ invOut, ushort* __restrict__ out) {
  int wave = threadIdx.x >> 6, lane = threadIdx.x & 63;
  int node = blockIdx.x * 4 + wave;
  if (node >= N_NODES) return;
  int beg = grp(rowptr, bsum, node), end = grp_end(rowptr, bsum, node);
  float s = 0.f;
  for (int e = beg + lane; e < end; e += 64) {
    float ev = __expf(slogit[e]);
    alphaE[e] = ev;
    s += ev;
  }
  s = wave_reduce_sum(s);
  float inv = (s > 0.f) ? 1.f / s : 0.f;
  if (lane == 0) invOut[node] = inv;

  int half = lane >> 5, hl = lane & 31;
  float acc[8] = {};
  int e = beg + half;
  for (; e + 6 < end; e += 8) {  // 4 edges per half-wave in flight
    int s0 = ssrc[e], s1 = ssrc[e + 2], s2 = ssrc[e + 4], s3 = ssrc[e + 6];
    float e0 = __expf(slogit[e]);
    float e1 = __expf(slogit[e + 2]);
    float e2 = __expf(slogit[e + 4]);
    float e3 = __expf(slogit[e + 6]);
    u16x8 h0 = *(const u16x8*)(feat + (size_t)s0 * D_LAT + hl * 8);
    u16x8 h1 = *(const u16x8*)(feat + (size_t)s1 * D_LAT + hl * 8);
    u16x8 h2 = *(const u16x8*)(feat + (size_t)s2 * D_LAT + hl * 8);
    u16x8 h3 = *(const u16x8*)(feat + (size_t)s3 * D_LAT + hl * 8);
#pragma unroll
    for (int q = 0; q < 8; q++) acc[q] += e0 * b2f(h0[q]);
#pragma unroll
    for (int q = 0; q < 8; q++) acc[q] += e1 * b2f(h1[q]);
#pragma unroll
    for (int q = 0; q < 8; q++) acc[q] += e2 * b2f(h2[q]);
#pragma unroll
    for (int q = 0; q < 8; q++) acc[q] += e3 * b2f(h3[q]);
  }
  for (; e < end; e += 2) {
    float ev = __expf(slogit[e]);
    int s2 = ssrc[e];
    u16x8 h = *(const u16x8*)(feat + (size_t)s2 * D_LAT + hl * 8);
#pragma unroll
    for (int q = 0; q < 8; q++) acc[q] += ev * b2f(h[q]);
  }
#pragma unroll
  for (int q = 0; q < 8; q++) acc[q] += __shfl_xor(acc[q], 32, 64);
  if (half == 0) {
    u16x8 o;
#pragma unroll
    for (int q = 0; q < 8; q++) {
      float v = acc[q] * inv;
      o[q] = f2b(v > 0.f ? v : __expf(v) - 1.f);
    }
    *(u16x8*)(out + (size_t)node * D_LAT + hl * 8) = o;
  }
}

// weighted gather over 64-dim bf16 rows (no elu — fused into next GEMM).
// Unnormalized e-weights from alphaE; scale by inv[node] at the end.
// One wave per node; quarter-waves (16 lanes x ushort4 = 128B row), 2-unroll.
__global__ __launch_bounds__(256) void agg_emb(
    const ushort* __restrict__ feat, const int* __restrict__ rowptr,
    const int* __restrict__ bsum, const int* __restrict__ ssrc,
    const float* __restrict__ alphaE, const float* __restrict__ invArr,
    ushort* __restrict__ out) {
  int wave = threadIdx.x >> 6, lane = threadIdx.x & 63;
  int node = blockIdx.x * 4 + wave;
  if (node >= N_NODES) return;
  int beg = grp(rowptr, bsum, node), end = grp_end(rowptr, bsum, node);
  int q = lane >> 4, ql = lane & 15;
  float acc[4] = {};
  int e = beg + q;
  for (; e + 4 < end; e += 8) {  // 2 edges per quarter-wave in flight
    float a0 = alphaE[e], a1 = alphaE[e + 4];
    int s0 = ssrc[e], s1 = ssrc[e + 4];
    ushort4 h0 = *(const ushort4*)(feat + (size_t)s0 * D_EMB + ql * 4);
    ushort4 h1 = *(const ushort4*)(feat + (size_t)s1 * D_EMB + ql * 4);
    acc[0] += a0 * b2f(h0.x) + a1 * b2f(h1.x);
    acc[1] += a0 * b2f(h0.y) + a1 * b2f(h1.y);
    acc[2] += a0 * b2f(h0.z) + a1 * b2f(h1.z);
    acc[3] += a0 * b2f(h0.w) + a1 * b2f(h1.w);
  }
  for (; e < end; e += 4) {
    float a = alphaE[e];
    int s = ssrc[e];
    ushort4 h = *(const ushort4*)(feat + (size_t)s * D_EMB + ql * 4);
    acc[0] += a * b2f(h.x);
    acc[1] += a * b2f(h.y);
    acc[2] += a * b2f(h.z);
    acc[3] += a * b2f(h.w);
  }
#pragma unroll
  for (int k = 0; k < 4; k++) {
    acc[k] += __shfl_xor(acc[k], 16, 64);
    acc[k] += __shfl_xor(acc[k], 32, 64);
  }
  if (q == 0) {
    float inv = invArr[node];
    ushort4 o;
    o.x = f2b(acc[0] * inv); o.y = f2b(acc[1] * inv);
    o.z = f2b(acc[2] * inv); o.w = f2b(acc[3] * inv);
    *(ushort4*)(out + (size_t)node * D_EMB + ql * 4) = o;
  }
}

extern "C" void kernel_launch(void* const* d_in, const int* in_sizes, int n_in,
                              void* d_out, int out_size, void* d_ws,
                              size_t ws_size, hipStream_t stream) {
  const float* x = (const float*)d_in[0];
  const float* W1 = (const float*)d_in[1];
  const float* a1s = (const float*)d_in[2];
  const float* a1d = (const float*)d_in[3];
  const float* W2 = (const float*)d_in[4];
  const int* ge = (const int*)d_in[5];
  const int* esrc = ge;
  const int* edst = ge + N_EDGES;

  float* out = (float*)d_out;
  float* emb = out;                              // [N, 64]
  float* recon = out + (size_t)N_NODES * D_EMB;  // [N, 512]

  char* w = (char*)d_ws;
  ushort* h1b = (ushort*)w;    w += (size_t)N_NODES * D_LAT * 2;  // reused as decb
  ushort* interb = (ushort*)w; w += (size_t)N_NODES * D_LAT * 2;  // reused as aggEb
  ushort* embb = (ushort*)w;   w += (size_t)N_NODES * D_EMB * 2;
  ushort* W1b = (ushort*)w;    w += (size_t)D_IN * D_LAT * 2;
  ushort* W1tb = (ushort*)w;   w += (size_t)D_LAT * D_IN * 2;
  ushort* W2b = (ushort*)w;    w += (size_t)D_LAT * D_EMB * 2;
  ushort* W2tb = (ushort*)w;   w += (size_t)D_EMB * D_LAT * 2;
  float* als = (float*)w;      w += (size_t)N_NODES * 4;
  float* ald = (float*)w;      w += (size_t)N_NODES * 4;  // reused as invArr
  int* counts = (int*)w;       w += (size_t)N_NODES * 4;  // adjacent to fill:
  int* fill = (int*)w;         w += (size_t)N_NODES * 4;  // one memset covers both
  int* rowptr = (int*)w;       w += (size_t)(N_NODES + 4) * 4;
  int* bsum = (int*)w;         w += 128 * 4;
  int* ssrc = (int*)w;         w += (size_t)N_EDGES * 4;
  float* slogit = (float*)w;   w += (size_t)N_EDGES * 4;
  float* alphaE = (float*)w;   w += (size_t)N_EDGES * 4;

  hipMemsetAsync(counts, 0, (size_t)N_NODES * 8, stream);  // counts + fill

  dim3 b256(256), b512(512);
  const int MB = (N_NODES + 127) / 128;  // 391

  // 0. weight conversions + edge histogram (one pass)
  conv_weights_hist<<<(N_EDGES + 255) / 256, b256, 0, stream>>>(
      W1, W2, W1b, W1tb, W2b, W2tb, edst, counts);

  // 1. h1 = x @ W1 (A f32 staged inline; BN=256 -> x read once) + fused
  //    logits als/ald from f32 accumulators
  gemm_mfma<128, 256, 2, 4, 1, 0, 1, 0, 1><<<dim3(1, MB), b512, 0, stream>>>(
      x, W1tb, (float*)nullptr, h1b, N_NODES, D_LAT, D_IN, a1s, a1d, als, ald);
  // 2-3. CSR by dst (2-phase scan; consumers add bsum inline)
  scan_phase1<<<SCAN_NBLK, 512, 0, stream>>>(counts, rowptr, bsum);
  scan_phase2<<<1, 128, 0, stream>>>(bsum);
  scatter_kernel<<<(N_EDGES + 255) / 256, b256, 0, stream>>>(
      esrc, edst, als, ald, rowptr, bsum, fill, ssrc, slogit);
  // 4. inter = elu(softmax-agg of h1); unnorm e + inv persisted for agg_emb
  float* invArr = ald;  // ald dead after scatter
  agg_bf16_sm<<<(N_NODES + 3) / 4, b256, 0, stream>>>(
      h1b, rowptr, bsum, ssrc, slogit, alphaE, invArr, interb);
  // 5. emb = inter @ W2 (f32 to d_out + bf16 copy)
  gemm_mfma<128, 64, 2, 2, 0, 1, 1, 0, 0><<<dim3(1, MB), b256, 0, stream>>>(
      interb, W2tb, emb, embb, N_NODES, D_EMB, D_LAT, nullptr, nullptr,
      nullptr, nullptr);
  // 6. aggE = softmax-agg of emb (linearity: agg(emb@W2^T)=agg(emb)@W2^T)
  ushort* aggEb = interb;
  agg_emb<<<(N_NODES + 3) / 4, b256, 0, stream>>>(embb, rowptr, bsum, ssrc,
                                                  alphaE, invArr, aggEb);
  // 7. dec = elu(aggE @ W2^T) (ELU fused) -> reuse h1b
  ushort* decb = h1b;
  gemm_mfma<128, 256, 2, 4, 0, 0, 1, 1, 0><<<dim3(1, MB), b512, 0, stream>>>(
      aggEb, W2b, (float*)nullptr, decb, N_NODES, D_LAT, D_EMB, nullptr,
      nullptr, nullptr, nullptr);
  // 8. recon = dec @ W1^T (f32 to d_out)
  gemm_mfma<128, 256, 2, 4, 0, 1, 0, 0, 0><<<dim3(D_IN / 256, MB), b512, 0,
                                              stream>>>(
      decb, W1b, recon, (ushort*)nullptr, N_NODES, D_IN, D_LAT, nullptr,
      nullptr, nullptr, nullptr);
}